// Round 2
// baseline (1220.954 us; speedup 1.0000x reference)
//
#include <hip/hip_runtime.h>
#include <math.h>

#define TT  100
#define CIN 400
#define H1  256
#define NS  32
#define NP  96
#define H3  512
#define H2C 128
#define BB  2
#define IJ  10000

// ---- static scratch (floats), fully rewritten each call ----
// xT     @ 0         : 2*400*100    =    80000
// h1     @ 80000     : 2*256*100    =    51200
// h2     @ 131200    : 51200
// sb     @ 182400    : 51200
// eb     @ 233600    : 51200
// pf     @ 284800    : 51200
// A      @ 336000    : 2*512*32*100 = 3276800
// cm2    @ 3612800   : 2*512*10000  = 10240000
// c3     @ 13852800  : 2*128*10000  = 2560000
// c4     @ 16412800  : 2560000
// total 18972800 floats = 75.9 MB
#define OFF_XT   0
#define OFF_H1   80000
#define OFF_H2   131200
#define OFF_SB   182400
#define OFF_EB   233600
#define OFF_PF   284800
#define OFF_A    336000
#define OFF_CM2  3612800
#define OFF_C3   13852800
#define OFF_C4   16412800
#define G_TOTAL  18972800

__device__ __align__(16) float g_buf[G_TOTAL];

// ---------- transpose x: (B,T,C) -> (B,C,T) ----------
__global__ void k_xt(const float* __restrict__ x) {
    int id = blockIdx.x * 256 + threadIdx.x;
    if (id >= BB * TT * CIN) return;
    int c = id % CIN, t = (id / CIN) % TT, b = id / (CIN * TT);
    g_buf[OFF_XT + (b * CIN + c) * TT + t] = x[id];
}

// ---------- generic conv1d k=3 pad=1 + relu ----------
__global__ void k_conv_g(int in_off, const float* __restrict__ w,
                         const float* __restrict__ bias, int out_off,
                         int ipg, int opg, int cinTot) {
    int id = blockIdx.x * 256 + threadIdx.x;
    if (id >= BB * H1 * TT) return;
    int t = id % TT, o = (id / TT) % H1, b = id / (TT * H1);
    const float* ip = g_buf + in_off + (b * cinTot + (o / opg) * ipg) * TT + t;
    const float* wp = w + o * ipg * 3;
    float acc = bias[o];
    for (int ci = 0; ci < ipg; ++ci) {
        float v0 = (t > 0)      ? ip[ci * TT - 1] : 0.f;
        float v1 = ip[ci * TT];
        float v2 = (t < TT - 1) ? ip[ci * TT + 1] : 0.f;
        acc = fmaf(v0, wp[ci * 3 + 0], acc);
        acc = fmaf(v1, wp[ci * 3 + 1], acc);
        acc = fmaf(v2, wp[ci * 3 + 2], acc);
    }
    g_buf[out_off + id] = fmaxf(acc, 0.f);
}

// ---------- 1x1 head: sigmoid ----------
__global__ void k_head(int in_off, const float* __restrict__ w,
                       const float* __restrict__ bias, float* __restrict__ out) {
    int id = threadIdx.x;
    if (id >= BB * TT) return;
    int t = id % TT, b = id / TT;
    const float* ip = g_buf + in_off + b * H1 * TT + t;
    float acc = bias[0];
    for (int c = 0; c < H1; ++c) acc = fmaf(ip[c * TT], w[c], acc);
    out[id] = 1.f / (1.f + expf(-acc));
}

// ---------- A[b,o,n,t] = sum_c pf[b,c,t] * w3d[o,c,n] ----------
__global__ void k_A(const float* __restrict__ w3d) {
    int id = blockIdx.x * 256 + threadIdx.x;   // B*512*32*25
    if (id >= BB * H3 * NS * 25) return;
    int x = id % 25, n = (id / 25) % NS, o = (id / (25 * NS)) % H3, b = id / (25 * NS * H3);
    const float4* pp = (const float4*)(g_buf + OFF_PF + b * H1 * TT) + x;
    const float* wp = w3d + o * H1 * NS + n;
    float4 acc = {0.f, 0.f, 0.f, 0.f};
    #pragma unroll 4
    for (int c = 0; c < H1; ++c) {
        float4 v = pp[c * 25];
        float ww = wp[c * NS];
        acc.x = fmaf(v.x, ww, acc.x);
        acc.y = fmaf(v.y, ww, acc.y);
        acc.z = fmaf(v.z, ww, acc.z);
        acc.w = fmaf(v.w, ww, acc.w);
    }
    ((float4*)(g_buf + OFF_A))[id] = acc;
}

// ---------- boundary-matching + conv3d fused ----------
__global__ __launch_bounds__(256) void k_bm(const float* __restrict__ b3d) {
    __shared__ float Ash[4 * 3200];
    int b = blockIdx.z, og = blockIdx.y, tij = blockIdx.x;
    int tid = threadIdx.x;
    const float* Ab = g_buf + OFF_A + (b * H3 + og * 4) * 3200;
    for (int i = tid; i < 4 * 3200; i += 256) Ash[i] = Ab[i];
    __syncthreads();

    float acc[4][4];
    #pragma unroll
    for (int u = 0; u < 4; ++u)
        #pragma unroll
        for (int m = 0; m < 4; ++m) acc[u][m] = 0.f;

    int ijv[4]; bool valid[4]; double xmin[4], plen[4];
    #pragma unroll
    for (int u = 0; u < 4; ++u) {
        int q = tij * 1024 + u * 256 + tid;
        ijv[u] = q;
        int i = q / 100, j = q - i * 100;
        valid[u] = (q < IJ) && (i <= j);
        double len = (double)(j - i + 2);
        xmin[u] = (double)i - 0.5 * len;
        double xmx = (double)(j + 1) + 0.5 * len;
        plen[u] = (xmx - xmin[u]) / 95.0;
    }

    for (int k = 0; k < NP; ++k) {
        int nbase = (k / 3) * TT;
        double kd = (double)k;
        #pragma unroll
        for (int u = 0; u < 4; ++u) {
            if (!valid[u]) continue;
            double pk = __dmul_rn(plen[u], kd);       // match np rounding: mul then add
            double s  = __dadd_rn(xmin[u], pk);
            double tr = trunc(s);                     // modf trunc-toward-zero
            double dec = s - tr;
            int dn = (int)tr;
            int up = (int)ceil(s);
            float wd = (float)((1.0 - dec) * (1.0 / 3.0));
            float wu = (float)(dec * (1.0 / 3.0));
            bool okd = ((unsigned)dn < (unsigned)TT);
            bool oku = ((unsigned)up < (unsigned)TT);
            float wdm = okd ? wd : 0.f;
            float wum = oku ? wu : 0.f;
            int ad = nbase + (okd ? dn : 0);
            int au = nbase + (oku ? up : 0);
            #pragma unroll
            for (int m = 0; m < 4; ++m) {
                const float* As = Ash + m * 3200;
                acc[u][m] = fmaf(wdm, As[ad], fmaf(wum, As[au], acc[u][m]));
            }
        }
    }

    #pragma unroll
    for (int u = 0; u < 4; ++u) {
        if (ijv[u] < IJ) {
            #pragma unroll
            for (int m = 0; m < 4; ++m) {
                float v = acc[u][m] + b3d[og * 4 + m];
                g_buf[OFF_CM2 + (size_t)(b * H3 + og * 4 + m) * IJ + ijv[u]] = fmaxf(v, 0.f);
            }
        }
    }
}

// ---------- q1: 1x1 conv 512->128 + relu ----------
__global__ __launch_bounds__(256) void k_q1(const float* __restrict__ w,
                                            const float* __restrict__ bias) {
    __shared__ float inS[32][64];
    __shared__ float wS[128][33];
    int b = blockIdx.y;
    int ij0 = blockIdx.x * 64;
    int tid = threadIdx.x;
    int ql = tid >> 4, ijl = tid & 15;
    float acc[8][4];
    #pragma unroll
    for (int m = 0; m < 8; ++m)
        #pragma unroll
        for (int v = 0; v < 4; ++v) acc[m][v] = 0.f;

    const float* in = g_buf + OFF_CM2 + (size_t)b * H3 * IJ;
    for (int c0 = 0; c0 < H3; c0 += 32) {
        __syncthreads();
        for (int idx = tid; idx < 32 * 64; idx += 256) {
            int cc = idx >> 6, x = idx & 63;
            int ij = ij0 + x;
            inS[cc][x] = (ij < IJ) ? in[(size_t)(c0 + cc) * IJ + ij] : 0.f;
        }
        for (int idx = tid; idx < 128 * 32; idx += 256) {
            int q = idx >> 5, cc = idx & 31;
            wS[q][cc] = w[q * H3 + c0 + cc];
        }
        __syncthreads();
        for (int cc = 0; cc < 32; ++cc) {
            float x0 = inS[cc][ijl * 4 + 0];
            float x1 = inS[cc][ijl * 4 + 1];
            float x2 = inS[cc][ijl * 4 + 2];
            float x3 = inS[cc][ijl * 4 + 3];
            #pragma unroll
            for (int m = 0; m < 8; ++m) {
                float ww = wS[ql * 8 + m][cc];
                acc[m][0] = fmaf(x0, ww, acc[m][0]);
                acc[m][1] = fmaf(x1, ww, acc[m][1]);
                acc[m][2] = fmaf(x2, ww, acc[m][2]);
                acc[m][3] = fmaf(x3, ww, acc[m][3]);
            }
        }
    }
    #pragma unroll
    for (int m = 0; m < 8; ++m) {
        int q = ql * 8 + m;
        #pragma unroll
        for (int v = 0; v < 4; ++v) {
            int ij = ij0 + ijl * 4 + v;
            if (ij < IJ)
                g_buf[OFF_C3 + (size_t)(b * H2C + q) * IJ + ij] = fmaxf(acc[m][v] + bias[q], 0.f);
        }
    }
}

// ---------- 3x3 conv 128->128 pad 1 + relu ----------
__global__ __launch_bounds__(256) void k_c3x3(int in_off, const float* __restrict__ w,
                                              const float* __restrict__ bias, int out_off) {
    __shared__ float inS[4][34 * 35];
    __shared__ float wS[4][4][9];
    int bz = blockIdx.z; int b = bz >> 5; int qg = bz & 31;
    int ti0 = blockIdx.y * 32 - 1, tj0 = blockIdx.x * 32 - 1;
    int tid = threadIdx.x;
    int xi = tid & 15, yi = tid >> 4;
    float acc[4][2][2];
    #pragma unroll
    for (int m = 0; m < 4; ++m)
        #pragma unroll
        for (int oy = 0; oy < 2; ++oy)
            #pragma unroll
            for (int ox = 0; ox < 2; ++ox) acc[m][oy][ox] = 0.f;

    const float* in = g_buf + in_off + (size_t)b * H2C * IJ;
    for (int c0 = 0; c0 < H2C; c0 += 4) {
        __syncthreads();
        for (int idx = tid; idx < 4 * 34 * 34; idx += 256) {
            int cc = idx / 1156; int r = idx - cc * 1156; int y = r / 34; int x = r - y * 34;
            int gi = ti0 + y, gj = tj0 + x;
            float v = (gi >= 0 && gi < TT && gj >= 0 && gj < TT)
                        ? in[(size_t)(c0 + cc) * IJ + gi * TT + gj] : 0.f;
            inS[cc][y * 35 + x] = v;
        }
        if (tid < 144) {
            int cc = tid / 36; int r = tid - cc * 36; int m = r / 9; int kk = r - m * 9;
            wS[cc][m][kk] = w[(size_t)((qg * 4 + m) * H2C + c0 + cc) * 9 + kk];
        }
        __syncthreads();
        #pragma unroll
        for (int cc = 0; cc < 4; ++cc) {
            float t[4][4];
            #pragma unroll
            for (int dy = 0; dy < 4; ++dy)
                #pragma unroll
                for (int dx = 0; dx < 4; ++dx)
                    t[dy][dx] = inS[cc][(yi * 2 + dy) * 35 + xi * 2 + dx];
            #pragma unroll
            for (int m = 0; m < 4; ++m)
                #pragma unroll
                for (int oy = 0; oy < 2; ++oy)
                    #pragma unroll
                    for (int ox = 0; ox < 2; ++ox) {
                        float a = acc[m][oy][ox];
                        #pragma unroll
                        for (int ky = 0; ky < 3; ++ky)
                            #pragma unroll
                            for (int kx = 0; kx < 3; ++kx)
                                a = fmaf(t[oy + ky][ox + kx], wS[cc][m][ky * 3 + kx], a);
                        acc[m][oy][ox] = a;
                    }
        }
    }
    #pragma unroll
    for (int m = 0; m < 4; ++m) {
        int q = qg * 4 + m;
        #pragma unroll
        for (int oy = 0; oy < 2; ++oy)
            #pragma unroll
            for (int ox = 0; ox < 2; ++ox) {
                int oi = blockIdx.y * 32 + yi * 2 + oy;
                int oj = blockIdx.x * 32 + xi * 2 + ox;
                if (oi < TT && oj < TT)
                    g_buf[out_off + (size_t)(b * H2C + q) * IJ + oi * TT + oj] =
                        fmaxf(acc[m][oy][ox] + bias[q], 0.f);
            }
    }
}

// ---------- q4: 1x1 conv 128->2 + sigmoid -> d_out ----------
__global__ void k_q4(int in_off, const float* __restrict__ w,
                     const float* __restrict__ bias, float* __restrict__ out) {
    int id = blockIdx.x * 256 + threadIdx.x;   // B*2*IJ
    if (id >= BB * 2 * IJ) return;
    int ij = id % IJ; int q = (id / IJ) & 1; int b = id / (2 * IJ);
    const float* ip = g_buf + in_off + (size_t)b * H2C * IJ + ij;
    const float* wp = w + q * H2C;
    float acc = bias[q];
    #pragma unroll 4
    for (int c = 0; c < H2C; ++c) acc = fmaf(ip[(size_t)c * IJ], wp[c], acc);
    out[id] = 1.f / (1.f + expf(-acc));
}

extern "C" void kernel_launch(void* const* d_in, const int* in_sizes, int n_in,
                              void* d_out, int out_size, void* d_ws, size_t ws_size,
                              hipStream_t stream) {
    const float* x   = (const float*)d_in[0];
    const float* wb1 = (const float*)d_in[1];  const float* bb1 = (const float*)d_in[2];
    const float* wb2 = (const float*)d_in[3];  const float* bb2 = (const float*)d_in[4];
    const float* ws1 = (const float*)d_in[5];  const float* bs1 = (const float*)d_in[6];
    const float* ws2 = (const float*)d_in[7];  const float* bs2 = (const float*)d_in[8];
    const float* we1 = (const float*)d_in[9];  const float* be1 = (const float*)d_in[10];
    const float* we2 = (const float*)d_in[11]; const float* be2 = (const float*)d_in[12];
    const float* wp  = (const float*)d_in[13]; const float* bp  = (const float*)d_in[14];
    const float* w3d = (const float*)d_in[15]; const float* b3d = (const float*)d_in[16];
    const float* wq1 = (const float*)d_in[17]; const float* bq1 = (const float*)d_in[18];
    const float* wq2 = (const float*)d_in[19]; const float* bq2 = (const float*)d_in[20];
    const float* wq3 = (const float*)d_in[21]; const float* bq3 = (const float*)d_in[22];
    const float* wq4 = (const float*)d_in[23]; const float* bq4 = (const float*)d_in[24];
    float* out = (float*)d_out;

    k_xt<<<(BB * TT * CIN + 255) / 256, 256, 0, stream>>>(x);
    k_conv_g<<<200, 256, 0, stream>>>(OFF_XT, wb1, bb1, OFF_H1, 100, 64, CIN);
    k_conv_g<<<200, 256, 0, stream>>>(OFF_H1, wb2, bb2, OFF_H2, 64, 64, H1);
    k_conv_g<<<200, 256, 0, stream>>>(OFF_H2, ws1, bs1, OFF_SB, 64, 64, H1);
    k_conv_g<<<200, 256, 0, stream>>>(OFF_H2, we1, be1, OFF_EB, 64, 64, H1);
    k_head<<<1, 256, 0, stream>>>(OFF_SB, ws2, bs2, out + 40000);
    k_head<<<1, 256, 0, stream>>>(OFF_EB, we2, be2, out + 40200);
    k_conv_g<<<200, 256, 0, stream>>>(OFF_H2, wp, bp, OFF_PF, 256, 256, H1);
    k_A<<<(BB * H3 * NS * 25 + 255) / 256, 256, 0, stream>>>(w3d);
    k_bm<<<dim3(10, 128, 2), 256, 0, stream>>>(b3d);
    k_q1<<<dim3(157, 2), 256, 0, stream>>>(wq1, bq1);
    k_c3x3<<<dim3(4, 4, 64), 256, 0, stream>>>(OFF_C3, wq2, bq2, OFF_C4);
    k_c3x3<<<dim3(4, 4, 64), 256, 0, stream>>>(OFF_C4, wq3, bq3, OFF_C3);
    k_q4<<<(BB * 2 * IJ + 255) / 256, 256, 0, stream>>>(OFF_C3, wq4, bq4, out);
}

// Round 3
// 711.376 us; speedup vs baseline: 1.7163x; 1.7163x over previous
//
#include <hip/hip_runtime.h>
#include <hip/hip_bf16.h>
#include <math.h>

#define TT  100
#define CIN 400
#define H1  256
#define NS  32
#define NP  96
#define H3  512
#define H2C 128
#define BB  2
#define IJ  10000
#define PADW 102
#define PPIX 10432                 // padded pixels + slop
#define PSTRIDE (PPIX * H2C)       // ushorts per batch = 1,335,296

typedef __attribute__((ext_vector_type(8))) short bf16x8;
typedef __attribute__((ext_vector_type(4))) float f32x4;

// ---- static scratch (float units) ----
// fp32: xT 80000 | h1/h2/sb/eb/pf 51200 ea | A 3,276,800
// bf16 (ushort counts shown as fl/2):
//   cm2T 2*10000*512 ush -> 5,120,000 fl
//   P1/P2 2*PSTRIDE ush  -> 1,335,296 fl each
//   P3 2*10000*128 ush   -> 1,280,000 fl
//   wq1b 65,536 ush -> 32,768 fl ; wq2b/wq3b 147,456 ush -> 73,728 fl ea
#define OFF_XT   0
#define OFF_H1   80000
#define OFF_H2   131200
#define OFF_SB   182400
#define OFF_EB   233600
#define OFF_PF   284800
#define OFF_A    336000
#define OFF_CM2T 3612800
#define OFF_P1   8732800
#define OFF_P2   10068096
#define OFF_P3   11403392
#define OFF_WQ1B 12683392
#define OFF_WQ2B 12716160
#define OFF_WQ3B 12789888
#define G_TOTAL  12863616

__device__ __align__(16) float g_buf[G_TOTAL];

__device__ inline unsigned short f2bf(float f) {
    __hip_bfloat16 h = __float2bfloat16(f);
    return *(unsigned short*)&h;
}
__device__ inline float bf2f(unsigned short u) {
    union { unsigned int i; float f; } v; v.i = ((unsigned int)u) << 16; return v.f;
}

// ---------- transpose x: (B,T,C) -> (B,C,T) ----------
__global__ void k_xt(const float* __restrict__ x) {
    int id = blockIdx.x * 256 + threadIdx.x;
    if (id >= BB * TT * CIN) return;
    int c = id % CIN, t = (id / CIN) % TT, b = id / (CIN * TT);
    g_buf[OFF_XT + (b * CIN + c) * TT + t] = x[id];
}

// ---------- generic conv1d k=3 pad=1 + relu ----------
__global__ void k_conv_g(int in_off, const float* __restrict__ w,
                         const float* __restrict__ bias, int out_off,
                         int ipg, int opg, int cinTot) {
    int id = blockIdx.x * 256 + threadIdx.x;
    if (id >= BB * H1 * TT) return;
    int t = id % TT, o = (id / TT) % H1, b = id / (TT * H1);
    const float* ip = g_buf + in_off + (b * cinTot + (o / opg) * ipg) * TT + t;
    const float* wp = w + o * ipg * 3;
    float acc = bias[o];
    for (int ci = 0; ci < ipg; ++ci) {
        float v0 = (t > 0)      ? ip[ci * TT - 1] : 0.f;
        float v1 = ip[ci * TT];
        float v2 = (t < TT - 1) ? ip[ci * TT + 1] : 0.f;
        acc = fmaf(v0, wp[ci * 3 + 0], acc);
        acc = fmaf(v1, wp[ci * 3 + 1], acc);
        acc = fmaf(v2, wp[ci * 3 + 2], acc);
    }
    g_buf[out_off + id] = fmaxf(acc, 0.f);
}

// ---------- 1x1 head: sigmoid ----------
__global__ void k_head(int in_off, const float* __restrict__ w,
                       const float* __restrict__ bias, float* __restrict__ out) {
    int id = threadIdx.x;
    if (id >= BB * TT) return;
    int t = id % TT, b = id / TT;
    const float* ip = g_buf + in_off + b * H1 * TT + t;
    float acc = bias[0];
    for (int c = 0; c < H1; ++c) acc = fmaf(ip[c * TT], w[c], acc);
    out[id] = 1.f / (1.f + expf(-acc));
}

// ---------- A[b,o,n,t] = sum_c pf[b,c,t] * w3d[o,c,n] ----------
__global__ void k_A(const float* __restrict__ w3d) {
    int id = blockIdx.x * 256 + threadIdx.x;   // B*512*32*25
    if (id >= BB * H3 * NS * 25) return;
    int x = id % 25, n = (id / 25) % NS, o = (id / (25 * NS)) % H3, b = id / (25 * NS * H3);
    const float4* pp = (const float4*)(g_buf + OFF_PF + b * H1 * TT) + x;
    const float* wp = w3d + o * H1 * NS + n;
    float4 acc = {0.f, 0.f, 0.f, 0.f};
    #pragma unroll 4
    for (int c = 0; c < H1; ++c) {
        float4 v = pp[c * 25];
        float ww = wp[c * NS];
        acc.x = fmaf(v.x, ww, acc.x);
        acc.y = fmaf(v.y, ww, acc.y);
        acc.z = fmaf(v.z, ww, acc.z);
        acc.w = fmaf(v.w, ww, acc.w);
    }
    ((float4*)(g_buf + OFF_A))[id] = acc;
}

// ---------- boundary-matching + conv3d fused; writes cm2T bf16 [b][ij][512] ----------
__global__ __launch_bounds__(256) void k_bm(const float* __restrict__ b3d) {
    __shared__ float Ash[4 * 3200];
    int b = blockIdx.z, og = blockIdx.y, tij = blockIdx.x;
    int tid = threadIdx.x;
    const float* Ab = g_buf + OFF_A + (b * H3 + og * 4) * 3200;
    for (int i = tid; i < 4 * 3200; i += 256) Ash[i] = Ab[i];
    __syncthreads();

    float acc[4][4];
    #pragma unroll
    for (int u = 0; u < 4; ++u)
        #pragma unroll
        for (int m = 0; m < 4; ++m) acc[u][m] = 0.f;

    int ijv[4]; bool valid[4]; double xmin[4], plen[4];
    #pragma unroll
    for (int u = 0; u < 4; ++u) {
        int q = tij * 1024 + u * 256 + tid;
        ijv[u] = q;
        int i = q / 100, j = q - i * 100;
        valid[u] = (q < IJ) && (i <= j);
        double len = (double)(j - i + 2);
        xmin[u] = (double)i - 0.5 * len;
        double xmx = (double)(j + 1) + 0.5 * len;
        plen[u] = (xmx - xmin[u]) / 95.0;
    }

    for (int k = 0; k < NP; ++k) {
        int nbase = (k / 3) * TT;
        double kd = (double)k;
        #pragma unroll
        for (int u = 0; u < 4; ++u) {
            if (!valid[u]) continue;
            double pk = __dmul_rn(plen[u], kd);
            double s  = __dadd_rn(xmin[u], pk);
            double tr = trunc(s);
            double dec = s - tr;
            int dn = (int)tr;
            int up = (int)ceil(s);
            float wd = (float)((1.0 - dec) * (1.0 / 3.0));
            float wu = (float)(dec * (1.0 / 3.0));
            bool okd = ((unsigned)dn < (unsigned)TT);
            bool oku = ((unsigned)up < (unsigned)TT);
            float wdm = okd ? wd : 0.f;
            float wum = oku ? wu : 0.f;
            int ad = nbase + (okd ? dn : 0);
            int au = nbase + (oku ? up : 0);
            #pragma unroll
            for (int m = 0; m < 4; ++m) {
                const float* As = Ash + m * 3200;
                acc[u][m] = fmaf(wdm, As[ad], fmaf(wum, As[au], acc[u][m]));
            }
        }
    }

    unsigned short* cm2T = (unsigned short*)(g_buf + OFF_CM2T);
    #pragma unroll
    for (int u = 0; u < 4; ++u) {
        if (ijv[u] < IJ) {
            float v0 = fmaxf(acc[u][0] + b3d[og * 4 + 0], 0.f);
            float v1 = fmaxf(acc[u][1] + b3d[og * 4 + 1], 0.f);
            float v2 = fmaxf(acc[u][2] + b3d[og * 4 + 2], 0.f);
            float v3 = fmaxf(acc[u][3] + b3d[og * 4 + 3], 0.f);
            uint2 pk;
            pk.x = (unsigned int)f2bf(v0) | ((unsigned int)f2bf(v1) << 16);
            pk.y = (unsigned int)f2bf(v2) | ((unsigned int)f2bf(v3) << 16);
            *(uint2*)(cm2T + ((size_t)b * IJ + ijv[u]) * 512 + og * 4) = pk;
        }
    }
}

// ---------- weight prep: fp32 -> bf16 (+ [q][c][tap] -> [q][tap*128+c]) ----------
__global__ void k_wprep(const float* __restrict__ wq1, const float* __restrict__ wq2,
                        const float* __restrict__ wq3) {
    int id = blockIdx.x * 256 + threadIdx.x;
    unsigned short* w1 = (unsigned short*)(g_buf + OFF_WQ1B);
    unsigned short* w2 = (unsigned short*)(g_buf + OFF_WQ2B);
    unsigned short* w3 = (unsigned short*)(g_buf + OFF_WQ3B);
    if (id < 65536) { w1[id] = f2bf(wq1[id]); return; }
    id -= 65536;
    if (id < 147456) {
        int q = id / 1152, k = id % 1152, tap = k >> 7, c = k & 127;
        w2[id] = f2bf(wq2[(q * 128 + c) * 9 + tap]); return;
    }
    id -= 147456;
    if (id < 147456) {
        int q = id / 1152, k = id % 1152, tap = k >> 7, c = k & 127;
        w3[id] = f2bf(wq3[(q * 128 + c) * 9 + tap]);
    }
}

// ---------- zero halos of P1/P2 (re-done every call; poison-safe) ----------
__global__ void k_halo() {
    int id = blockIdx.x * 256 + threadIdx.x;   // 2buf*2b*404px*32chunks = 51712
    if (id >= 51712) return;
    int c = id & 31;
    int h = (id >> 5) % 404;
    int bb = ((id >> 5) / 404) & 1;
    int buf = id / 25856;
    int pix;
    if (h < 102) pix = h;
    else if (h < 204) pix = 101 * PADW + (h - 102);
    else { int q = h - 204; pix = (1 + (q >> 1)) * PADW + ((q & 1) ? 101 : 0); }
    unsigned short* P = (unsigned short*)(g_buf + (buf ? OFF_P2 : OFF_P1))
                        + (size_t)bb * PSTRIDE + (size_t)pix * H2C;
    ((uint2*)P)[c] = make_uint2(0u, 0u);
}

// ---------- q1: 1x1 conv 512->128, MFMA, cm2T -> P1 (padded) ----------
__global__ __launch_bounds__(256) void k_q1m(const float* __restrict__ bias) {
    const unsigned short* A  = (const unsigned short*)(g_buf + OFF_CM2T);
    const unsigned short* Bw = (const unsigned short*)(g_buf + OFF_WQ1B);
    unsigned short* P1 = (unsigned short*)(g_buf + OFF_P1);
    int m0 = blockIdx.x * 16;
    int wv = threadIdx.x >> 6, lane = threadIdx.x & 63;
    int r = lane & 15, g = lane >> 4;
    int q0 = wv * 32;
    const unsigned short* arow  = A  + (size_t)(m0 + r) * 512 + g * 8;
    const unsigned short* b0row = Bw + (size_t)(q0 + r) * 512 + g * 8;
    const unsigned short* b1row = Bw + (size_t)(q0 + 16 + r) * 512 + g * 8;
    f32x4 acc0 = {0.f, 0.f, 0.f, 0.f}, acc1 = {0.f, 0.f, 0.f, 0.f};
    #pragma unroll 4
    for (int ks = 0; ks < 16; ++ks) {
        bf16x8 a  = *(const bf16x8*)(arow  + ks * 32);
        bf16x8 b0 = *(const bf16x8*)(b0row + ks * 32);
        bf16x8 b1 = *(const bf16x8*)(b1row + ks * 32);
        acc0 = __builtin_amdgcn_mfma_f32_16x16x32_bf16(a, b0, acc0, 0, 0, 0);
        acc1 = __builtin_amdgcn_mfma_f32_16x16x32_bf16(a, b1, acc1, 0, 0, 0);
    }
    int bb = m0 / IJ;
    unsigned short* Pout = P1 + (size_t)bb * PSTRIDE;
    float bi0 = bias[q0 + r], bi1 = bias[q0 + 16 + r];
    #pragma unroll
    for (int reg = 0; reg < 4; ++reg) {
        int p = m0 + g * 4 + reg;
        int ij = p - bb * IJ;
        int i = ij / 100, j = ij - i * 100;
        size_t base = (size_t)((i + 1) * PADW + j + 1) * H2C;
        Pout[base + q0 + r]      = f2bf(fmaxf(acc0[reg] + bi0, 0.f));
        Pout[base + q0 + 16 + r] = f2bf(fmaxf(acc1[reg] + bi1, 0.f));
    }
}

// ---------- 3x3 conv 128->128, MFMA implicit GEMM over padded layout ----------
__global__ __launch_bounds__(256) void k_c3m(int in_off, int w_off,
                                             const float* __restrict__ bias,
                                             int out_off, int outpad) {
    const unsigned short* Pin = (const unsigned short*)(g_buf + in_off);
    const unsigned short* wB  = (const unsigned short*)(g_buf + w_off);
    unsigned short* Pout = (unsigned short*)(g_buf + out_off);
    int jt = blockIdx.x, i = blockIdx.y, b = blockIdx.z;
    int j0 = (jt == 6) ? 84 : jt * 16;
    int wv = threadIdx.x >> 6, lane = threadIdx.x & 63;
    int r = lane & 15, g = lane >> 4;
    int q0 = wv * 32;
    const unsigned short* Ab = Pin + (size_t)b * PSTRIDE;
    f32x4 acc0 = {0.f, 0.f, 0.f, 0.f}, acc1 = {0.f, 0.f, 0.f, 0.f};
    #pragma unroll 1
    for (int ky = 0; ky < 3; ++ky) {
        #pragma unroll
        for (int kx = 0; kx < 3; ++kx) {
            int tap = ky * 3 + kx;
            const unsigned short* arow = Ab + (size_t)((i + ky) * PADW + j0 + r + kx) * H2C + g * 8;
            const unsigned short* b0r = wB + (size_t)(q0 + r) * 1152 + tap * 128 + g * 8;
            const unsigned short* b1r = wB + (size_t)(q0 + 16 + r) * 1152 + tap * 128 + g * 8;
            #pragma unroll
            for (int cc = 0; cc < 4; ++cc) {
                bf16x8 a  = *(const bf16x8*)(arow + cc * 32);
                bf16x8 b0 = *(const bf16x8*)(b0r + cc * 32);
                bf16x8 b1 = *(const bf16x8*)(b1r + cc * 32);
                acc0 = __builtin_amdgcn_mfma_f32_16x16x32_bf16(a, b0, acc0, 0, 0, 0);
                acc1 = __builtin_amdgcn_mfma_f32_16x16x32_bf16(a, b1, acc1, 0, 0, 0);
            }
        }
    }
    float bi0 = bias[q0 + r], bi1 = bias[q0 + 16 + r];
    unsigned short* Ob = Pout + (size_t)b * (outpad ? (size_t)PSTRIDE : (size_t)IJ * H2C);
    #pragma unroll
    for (int reg = 0; reg < 4; ++reg) {
        int j = j0 + g * 4 + reg;
        size_t base = outpad ? (size_t)((i + 1) * PADW + j + 1) * H2C
                             : (size_t)(i * 100 + j) * H2C;
        Ob[base + q0 + r]      = f2bf(fmaxf(acc0[reg] + bi0, 0.f));
        Ob[base + q0 + 16 + r] = f2bf(fmaxf(acc1[reg] + bi1, 0.f));
    }
}

// ---------- q4: 1x1 conv 128->2 + sigmoid, channel-last bf16 in ----------
__global__ void k_q4(const float* __restrict__ w, const float* __restrict__ bias,
                     float* __restrict__ out) {
    int id = blockIdx.x * 256 + threadIdx.x;   // B*IJ
    if (id >= BB * IJ) return;
    int b = id / IJ, ij = id % IJ;
    const unsigned short* row = (const unsigned short*)(g_buf + OFF_P3) + (size_t)id * H2C;
    float a0 = bias[0], a1 = bias[1];
    for (int c = 0; c < H2C; c += 8) {
        bf16x8 v = *(const bf16x8*)(row + c);
        #pragma unroll
        for (int t = 0; t < 8; ++t) {
            float f = bf2f((unsigned short)v[t]);
            a0 = fmaf(f, w[c + t], a0);
            a1 = fmaf(f, w[128 + c + t], a1);
        }
    }
    out[(size_t)(b * 2) * IJ + ij]     = 1.f / (1.f + expf(-a0));
    out[(size_t)(b * 2 + 1) * IJ + ij] = 1.f / (1.f + expf(-a1));
}

extern "C" void kernel_launch(void* const* d_in, const int* in_sizes, int n_in,
                              void* d_out, int out_size, void* d_ws, size_t ws_size,
                              hipStream_t stream) {
    const float* x   = (const float*)d_in[0];
    const float* wb1 = (const float*)d_in[1];  const float* bb1 = (const float*)d_in[2];
    const float* wb2 = (const float*)d_in[3];  const float* bb2 = (const float*)d_in[4];
    const float* ws1 = (const float*)d_in[5];  const float* bs1 = (const float*)d_in[6];
    const float* ws2 = (const float*)d_in[7];  const float* bs2 = (const float*)d_in[8];
    const float* we1 = (const float*)d_in[9];  const float* be1 = (const float*)d_in[10];
    const float* we2 = (const float*)d_in[11]; const float* be2 = (const float*)d_in[12];
    const float* wp  = (const float*)d_in[13]; const float* bp  = (const float*)d_in[14];
    const float* w3d = (const float*)d_in[15]; const float* b3d = (const float*)d_in[16];
    const float* wq1 = (const float*)d_in[17]; const float* bq1 = (const float*)d_in[18];
    const float* wq2 = (const float*)d_in[19]; const float* bq2 = (const float*)d_in[20];
    const float* wq3 = (const float*)d_in[21]; const float* bq3 = (const float*)d_in[22];
    const float* wq4 = (const float*)d_in[23]; const float* bq4 = (const float*)d_in[24];
    float* out = (float*)d_out;

    k_wprep<<<1408, 256, 0, stream>>>(wq1, wq2, wq3);
    k_halo<<<202, 256, 0, stream>>>();
    k_xt<<<(BB * TT * CIN + 255) / 256, 256, 0, stream>>>(x);
    k_conv_g<<<200, 256, 0, stream>>>(OFF_XT, wb1, bb1, OFF_H1, 100, 64, CIN);
    k_conv_g<<<200, 256, 0, stream>>>(OFF_H1, wb2, bb2, OFF_H2, 64, 64, H1);
    k_conv_g<<<200, 256, 0, stream>>>(OFF_H2, ws1, bs1, OFF_SB, 64, 64, H1);
    k_conv_g<<<200, 256, 0, stream>>>(OFF_H2, we1, be1, OFF_EB, 64, 64, H1);
    k_head<<<1, 256, 0, stream>>>(OFF_SB, ws2, bs2, out + 40000);
    k_head<<<1, 256, 0, stream>>>(OFF_EB, we2, be2, out + 40200);
    k_conv_g<<<200, 256, 0, stream>>>(OFF_H2, wp, bp, OFF_PF, 256, 256, H1);
    k_A<<<(BB * H3 * NS * 25 + 255) / 256, 256, 0, stream>>>(w3d);
    k_bm<<<dim3(10, 128, 2), 256, 0, stream>>>(b3d);
    k_q1m<<<1250, 256, 0, stream>>>(bq1);
    k_c3m<<<dim3(7, 100, 2), 256, 0, stream>>>(OFF_P1, OFF_WQ2B, bq2, OFF_P2, 1);
    k_c3m<<<dim3(7, 100, 2), 256, 0, stream>>>(OFF_P2, OFF_WQ3B, bq3, OFF_P3, 0);
    k_q4<<<(BB * IJ + 255) / 256, 256, 0, stream>>>(wq4, bq4, out);
}

// Round 4
// 604.913 us; speedup vs baseline: 2.0184x; 1.1760x over previous
//
#include <hip/hip_runtime.h>
#include <hip/hip_bf16.h>
#include <math.h>

#define TT  100
#define CIN 400
#define H1  256
#define NS  32
#define NP  96
#define H3  512
#define H2C 128
#define BB  2
#define IJ  10000
#define PADW 102
#define PPIX 10432
#define PSTRIDE (PPIX * H2C)

typedef __attribute__((ext_vector_type(8))) short bf16x8;
typedef __attribute__((ext_vector_type(4))) float f32x4;

// ---- static scratch (float units) ----
#define OFF_XT   0
#define OFF_H1   80000
#define OFF_H2   131200
#define OFF_SB   182400
#define OFF_EB   233600
#define OFF_PF   284800
#define OFF_A    336000      // A_T[b][3200][512] f32 = 3,276,800
#define OFF_CM2T 3612800     // bf16 [b][ij][512] = 5,120,000 fl
#define OFF_P1   8732800
#define OFF_P2   10068096
#define OFF_P3   11403392
#define OFF_WQ1B 12683392
#define OFF_WQ2B 12716160
#define OFF_WQ3B 12789888
#define OFF_DESC 12863616    // u32 [96][10240] = 983,040 fl
#define OFF_PFT  13846656    // bf16 [b][112][256] = 28,672 fl
#define OFF_W3B  13875328    // bf16 [n][o][c] 32*512*256 = 2,097,152 fl
#define G_TOTAL  15972480

__device__ __align__(16) float g_buf[G_TOTAL];

__device__ inline unsigned short f2bf(float f) {
    __hip_bfloat16 h = __float2bfloat16(f);
    return *(unsigned short*)&h;
}
__device__ inline float bf2f(unsigned short u) {
    union { unsigned int i; float f; } v; v.i = ((unsigned int)u) << 16; return v.f;
}

// ---------- transpose x: (B,T,C) -> (B,C,T) ----------
__global__ void k_xt(const float* __restrict__ x) {
    int id = blockIdx.x * 256 + threadIdx.x;
    if (id >= BB * TT * CIN) return;
    int c = id % CIN, t = (id / CIN) % TT, b = id / (CIN * TT);
    g_buf[OFF_XT + (b * CIN + c) * TT + t] = x[id];
}

// ---------- generic conv1d k=3 pad=1 + relu ----------
__global__ void k_conv_g(int in_off, const float* __restrict__ w,
                         const float* __restrict__ bias, int out_off,
                         int ipg, int opg, int cinTot) {
    int id = blockIdx.x * 256 + threadIdx.x;
    if (id >= BB * H1 * TT) return;
    int t = id % TT, o = (id / TT) % H1, b = id / (TT * H1);
    const float* ip = g_buf + in_off + (b * cinTot + (o / opg) * ipg) * TT + t;
    const float* wp = w + o * ipg * 3;
    float acc = bias[o];
    for (int ci = 0; ci < ipg; ++ci) {
        float v0 = (t > 0)      ? ip[ci * TT - 1] : 0.f;
        float v1 = ip[ci * TT];
        float v2 = (t < TT - 1) ? ip[ci * TT + 1] : 0.f;
        acc = fmaf(v0, wp[ci * 3 + 0], acc);
        acc = fmaf(v1, wp[ci * 3 + 1], acc);
        acc = fmaf(v2, wp[ci * 3 + 2], acc);
    }
    g_buf[out_off + id] = fmaxf(acc, 0.f);
}

// ---------- 1x1 head: sigmoid ----------
__global__ void k_head(int in_off, const float* __restrict__ w,
                       const float* __restrict__ bias, float* __restrict__ out) {
    int id = threadIdx.x;
    if (id >= BB * TT) return;
    int t = id % TT, b = id / TT;
    const float* ip = g_buf + in_off + b * H1 * TT + t;
    float acc = bias[0];
    for (int c = 0; c < H1; ++c) acc = fmaf(ip[c * TT], w[c], acc);
    out[id] = 1.f / (1.f + expf(-acc));
}

// ---------- pfT[b][t(112 pad)][c] bf16 from pf[b][c][t] ----------
__global__ void k_pfT() {
    int id = blockIdx.x * 256 + threadIdx.x;   // 2*112*256
    if (id >= BB * 112 * 256) return;
    int c = id & 255, t = (id >> 8) % 112, b = id / (112 * 256);
    unsigned short* pfT = (unsigned short*)(g_buf + OFF_PFT);
    float v = (t < TT) ? g_buf[OFF_PF + (b * H1 + c) * TT + t] : 0.f;
    pfT[id] = f2bf(v);
}

// ---------- w3b[n][o][c] bf16 from w3d[o][c][n], LDS transpose per o ----------
__global__ __launch_bounds__(256) void k_w3prep(const float* __restrict__ w3d) {
    __shared__ float tile[8192];
    int o = blockIdx.x, tid = threadIdx.x;
    const float* src = w3d + o * 8192;         // [c][n] contiguous for fixed o
    for (int idx = tid; idx < 8192; idx += 256) tile[idx] = src[idx];
    __syncthreads();
    int n = tid & 31, ch = tid >> 5;           // ch: chunk of 32 c
    unsigned short* w3b = (unsigned short*)(g_buf + OFF_W3B);
    unsigned int w[16];
    #pragma unroll
    for (int c2 = 0; c2 < 16; ++c2) {
        int c = ch * 32 + c2 * 2;
        w[c2] = (unsigned int)f2bf(tile[c * 32 + n]) |
                ((unsigned int)f2bf(tile[(c + 1) * 32 + n]) << 16);
    }
    uint4* dst = (uint4*)(w3b + ((size_t)n * 512 + o) * 256 + ch * 32);
    dst[0] = make_uint4(w[0], w[1], w[2], w[3]);
    dst[1] = make_uint4(w[4], w[5], w[6], w[7]);
    dst[2] = make_uint4(w[8], w[9], w[10], w[11]);
    dst[3] = make_uint4(w[12], w[13], w[14], w[15]);
}

// ---------- A_T[b][n*100+t][o] = sum_c pf[b,c,t]*w3d[o,c,n]  (MFMA) ----------
__global__ __launch_bounds__(256) void k_Am() {
    int mt = blockIdx.x, nt = blockIdx.y, bn = blockIdx.z;
    int b = bn >> 5, n = bn & 31;
    int wv = threadIdx.x >> 6, lane = threadIdx.x & 63;
    int r = lane & 15, g = lane >> 4;
    const unsigned short* ap = (const unsigned short*)(g_buf + OFF_PFT)
                               + ((size_t)b * 112 + mt * 16 + r) * 256 + g * 8;
    const unsigned short* bp = (const unsigned short*)(g_buf + OFF_W3B)
                               + ((size_t)n * 512 + nt * 128 + wv * 32 + r) * 256 + g * 8;
    f32x4 acc0 = {0.f, 0.f, 0.f, 0.f}, acc1 = {0.f, 0.f, 0.f, 0.f};
    #pragma unroll
    for (int ks = 0; ks < 8; ++ks) {
        bf16x8 a  = *(const bf16x8*)(ap + ks * 32);
        bf16x8 b0 = *(const bf16x8*)(bp + ks * 32);
        bf16x8 b1 = *(const bf16x8*)(bp + 16 * 256 + ks * 32);
        acc0 = __builtin_amdgcn_mfma_f32_16x16x32_bf16(a, b0, acc0, 0, 0, 0);
        acc1 = __builtin_amdgcn_mfma_f32_16x16x32_bf16(a, b1, acc1, 0, 0, 0);
    }
    float* AT = g_buf + OFF_A + (size_t)b * 3200 * 512;
    #pragma unroll
    for (int reg = 0; reg < 4; ++reg) {
        int t = mt * 16 + g * 4 + reg;
        if (t < TT) {
            AT[(size_t)(n * 100 + t) * 512 + nt * 128 + wv * 32 + r]      = acc0[reg];
            AT[(size_t)(n * 100 + t) * 512 + nt * 128 + wv * 32 + 16 + r] = acc1[reg];
        }
    }
}

// ---------- desc[k][q]: exact f64 sample math, once per (ij,k) ----------
__global__ void k_desc() {
    int id = blockIdx.x * 256 + threadIdx.x;   // 96*10240
    if (id >= NP * 10240) return;
    int k = id / 10240, q = id - k * 10240;
    int i = q / 100, j = q - i * 100;
    unsigned int nb = (unsigned int)((k / 3) * 100);
    unsigned int d;
    if (q >= IJ || i > j) {
        d = nb | (2u << 12);
    } else {
        double len = (double)(j - i + 2);
        double xmn = (double)i - 0.5 * len;
        double xmx = (double)(j + 1) + 0.5 * len;
        double plen = (xmx - xmn) / 95.0;
        double s = __dadd_rn(xmn, __dmul_rn(plen, (double)k));
        double tr = trunc(s);
        double dec = s - tr;
        int dn = (int)tr;
        int up = (int)ceil(s);
        bool okd = (unsigned)dn < (unsigned)TT;
        bool oku = (unsigned)up < (unsigned)TT;
        if (!okd) d = nb | (2u << 12);
        else if (oku && up == dn + 1) {
            unsigned int dfx = (unsigned int)__double2int_rn(dec * 65535.0);
            d = (nb + dn) | (dfx << 16);                       // mode 0: two taps
        } else if (oku) {                                       // up==dn: w = 1/3
            d = (nb + dn) | (1u << 12);
        } else {                                                // dn=99, s in (99,100)
            unsigned int dfx = (unsigned int)__double2int_rn(dec * 65535.0);
            d = (nb + dn) | (1u << 12) | (dfx << 16);           // mode 1: w=(1-dec)/3
        }
    }
    ((unsigned int*)(g_buf + OFF_DESC))[id] = d;
}

// ---------- BM gather + conv3d bias/relu, 16 ch per block ----------
__global__ __launch_bounds__(256) void k_bm2(const float* __restrict__ b3d) {
    __shared__ float4 Ash[800 * 4];            // [t-window 800][16ch], xor-swizzled
    int tij = blockIdx.x, og = blockIdx.y, b = blockIdx.z;
    int tid = threadIdx.x;
    float acc[4][16];
    #pragma unroll
    for (int u = 0; u < 4; ++u)
        #pragma unroll
        for (int c = 0; c < 16; ++c) acc[u][c] = 0.f;
    int q0 = tij * 1024 + tid;
    const float* AT = g_buf + OFF_A + (size_t)b * 3200 * 512 + og * 16;
    const unsigned int* desc = (const unsigned int*)(g_buf + OFF_DESC);

    for (int st = 0; st < 4; ++st) {
        __syncthreads();
        for (int idx = tid; idx < 3200; idx += 256) {
            int tt = idx >> 2, c4 = idx & 3;
            Ash[(tt << 2) | (c4 ^ (tt & 3))] =
                *(const float4*)(AT + (size_t)(st * 800 + tt) * 512 + c4 * 4);
        }
        __syncthreads();
        for (int kk = 0; kk < 24; ++kk) {
            const unsigned int* dk = desc + (st * 24 + kk) * 10240 + q0;
            #pragma unroll
            for (int u = 0; u < 4; ++u) {
                unsigned int d = dk[u * 256];
                int t = (int)(d & 0xFFFu) - st * 800;
                int mode = (d >> 12) & 3;
                float dec = (float)(d >> 16) * (1.f / 65535.f);
                float w0 = (mode == 2) ? 0.f : (1.f - dec) * (1.f / 3.f);
                float w1 = (mode == 0) ? dec * (1.f / 3.f) : 0.f;
                int t1 = (mode == 0) ? t + 1 : t;
                #pragma unroll
                for (int c4 = 0; c4 < 4; ++c4) {
                    float4 a0 = Ash[(t << 2) | (c4 ^ (t & 3))];
                    float4 a1 = Ash[(t1 << 2) | (c4 ^ (t1 & 3))];
                    acc[u][c4 * 4 + 0] = fmaf(w0, a0.x, fmaf(w1, a1.x, acc[u][c4 * 4 + 0]));
                    acc[u][c4 * 4 + 1] = fmaf(w0, a0.y, fmaf(w1, a1.y, acc[u][c4 * 4 + 1]));
                    acc[u][c4 * 4 + 2] = fmaf(w0, a0.z, fmaf(w1, a1.z, acc[u][c4 * 4 + 2]));
                    acc[u][c4 * 4 + 3] = fmaf(w0, a0.w, fmaf(w1, a1.w, acc[u][c4 * 4 + 3]));
                }
            }
        }
    }
    unsigned short* cm2T = (unsigned short*)(g_buf + OFF_CM2T);
    #pragma unroll
    for (int u = 0; u < 4; ++u) {
        int q = q0 + u * 256;
        if (q < IJ) {
            unsigned int w[8];
            #pragma unroll
            for (int c2 = 0; c2 < 8; ++c2) {
                float v0 = fmaxf(acc[u][c2 * 2]     + b3d[og * 16 + c2 * 2],     0.f);
                float v1 = fmaxf(acc[u][c2 * 2 + 1] + b3d[og * 16 + c2 * 2 + 1], 0.f);
                w[c2] = (unsigned int)f2bf(v0) | ((unsigned int)f2bf(v1) << 16);
            }
            uint4* dst = (uint4*)(cm2T + ((size_t)b * IJ + q) * 512 + og * 16);
            dst[0] = make_uint4(w[0], w[1], w[2], w[3]);
            dst[1] = make_uint4(w[4], w[5], w[6], w[7]);
        }
    }
}

// ---------- weight prep for 2D head ----------
__global__ void k_wprep(const float* __restrict__ wq1, const float* __restrict__ wq2,
                        const float* __restrict__ wq3) {
    int id = blockIdx.x * 256 + threadIdx.x;
    unsigned short* w1 = (unsigned short*)(g_buf + OFF_WQ1B);
    unsigned short* w2 = (unsigned short*)(g_buf + OFF_WQ2B);
    unsigned short* w3 = (unsigned short*)(g_buf + OFF_WQ3B);
    if (id < 65536) { w1[id] = f2bf(wq1[id]); return; }
    id -= 65536;
    if (id < 147456) {
        int q = id / 1152, k = id % 1152, tap = k >> 7, c = k & 127;
        w2[id] = f2bf(wq2[(q * 128 + c) * 9 + tap]); return;
    }
    id -= 147456;
    if (id < 147456) {
        int q = id / 1152, k = id % 1152, tap = k >> 7, c = k & 127;
        w3[id] = f2bf(wq3[(q * 128 + c) * 9 + tap]);
    }
}

// ---------- zero halos of P1/P2 ----------
__global__ void k_halo() {
    int id = blockIdx.x * 256 + threadIdx.x;
    if (id >= 51712) return;
    int c = id & 31;
    int h = (id >> 5) % 404;
    int bb = ((id >> 5) / 404) & 1;
    int buf = id / 25856;
    int pix;
    if (h < 102) pix = h;
    else if (h < 204) pix = 101 * PADW + (h - 102);
    else { int q = h - 204; pix = (1 + (q >> 1)) * PADW + ((q & 1) ? 101 : 0); }
    unsigned short* P = (unsigned short*)(g_buf + (buf ? OFF_P2 : OFF_P1))
                        + (size_t)bb * PSTRIDE + (size_t)pix * H2C;
    ((uint2*)P)[c] = make_uint2(0u, 0u);
}

// ---------- q1: 1x1 conv 512->128, MFMA ----------
__global__ __launch_bounds__(256) void k_q1m(const float* __restrict__ bias) {
    const unsigned short* A  = (const unsigned short*)(g_buf + OFF_CM2T);
    const unsigned short* Bw = (const unsigned short*)(g_buf + OFF_WQ1B);
    unsigned short* P1 = (unsigned short*)(g_buf + OFF_P1);
    int m0 = blockIdx.x * 16;
    int wv = threadIdx.x >> 6, lane = threadIdx.x & 63;
    int r = lane & 15, g = lane >> 4;
    int q0 = wv * 32;
    const unsigned short* arow  = A  + (size_t)(m0 + r) * 512 + g * 8;
    const unsigned short* b0row = Bw + (size_t)(q0 + r) * 512 + g * 8;
    const unsigned short* b1row = Bw + (size_t)(q0 + 16 + r) * 512 + g * 8;
    f32x4 acc0 = {0.f, 0.f, 0.f, 0.f}, acc1 = {0.f, 0.f, 0.f, 0.f};
    #pragma unroll 4
    for (int ks = 0; ks < 16; ++ks) {
        bf16x8 a  = *(const bf16x8*)(arow  + ks * 32);
        bf16x8 b0 = *(const bf16x8*)(b0row + ks * 32);
        bf16x8 b1 = *(const bf16x8*)(b1row + ks * 32);
        acc0 = __builtin_amdgcn_mfma_f32_16x16x32_bf16(a, b0, acc0, 0, 0, 0);
        acc1 = __builtin_amdgcn_mfma_f32_16x16x32_bf16(a, b1, acc1, 0, 0, 0);
    }
    int bb = m0 / IJ;
    unsigned short* Pout = P1 + (size_t)bb * PSTRIDE;
    float bi0 = bias[q0 + r], bi1 = bias[q0 + 16 + r];
    #pragma unroll
    for (int reg = 0; reg < 4; ++reg) {
        int p = m0 + g * 4 + reg;
        int ij = p - bb * IJ;
        int i = ij / 100, j = ij - i * 100;
        size_t base = (size_t)((i + 1) * PADW + j + 1) * H2C;
        Pout[base + q0 + r]      = f2bf(fmaxf(acc0[reg] + bi0, 0.f));
        Pout[base + q0 + 16 + r] = f2bf(fmaxf(acc1[reg] + bi1, 0.f));
    }
}

// ---------- 3x3 conv 128->128, MFMA implicit GEMM ----------
__global__ __launch_bounds__(256) void k_c3m(int in_off, int w_off,
                                             const float* __restrict__ bias,
                                             int out_off, int outpad) {
    const unsigned short* Pin = (const unsigned short*)(g_buf + in_off);
    const unsigned short* wB  = (const unsigned short*)(g_buf + w_off);
    unsigned short* Pout = (unsigned short*)(g_buf + out_off);
    int jt = blockIdx.x, i = blockIdx.y, b = blockIdx.z;
    int j0 = (jt == 6) ? 84 : jt * 16;
    int wv = threadIdx.x >> 6, lane = threadIdx.x & 63;
    int r = lane & 15, g = lane >> 4;
    int q0 = wv * 32;
    const unsigned short* Ab = Pin + (size_t)b * PSTRIDE;
    f32x4 acc0 = {0.f, 0.f, 0.f, 0.f}, acc1 = {0.f, 0.f, 0.f, 0.f};
    #pragma unroll 1
    for (int ky = 0; ky < 3; ++ky) {
        #pragma unroll
        for (int kx = 0; kx < 3; ++kx) {
            int tap = ky * 3 + kx;
            const unsigned short* arow = Ab + (size_t)((i + ky) * PADW + j0 + r + kx) * H2C + g * 8;
            const unsigned short* b0r = wB + (size_t)(q0 + r) * 1152 + tap * 128 + g * 8;
            const unsigned short* b1r = wB + (size_t)(q0 + 16 + r) * 1152 + tap * 128 + g * 8;
            #pragma unroll
            for (int cc = 0; cc < 4; ++cc) {
                bf16x8 a  = *(const bf16x8*)(arow + cc * 32);
                bf16x8 b0 = *(const bf16x8*)(b0r + cc * 32);
                bf16x8 b1 = *(const bf16x8*)(b1r + cc * 32);
                acc0 = __builtin_amdgcn_mfma_f32_16x16x32_bf16(a, b0, acc0, 0, 0, 0);
                acc1 = __builtin_amdgcn_mfma_f32_16x16x32_bf16(a, b1, acc1, 0, 0, 0);
            }
        }
    }
    float bi0 = bias[q0 + r], bi1 = bias[q0 + 16 + r];
    unsigned short* Ob = Pout + (size_t)b * (outpad ? (size_t)PSTRIDE : (size_t)IJ * H2C);
    #pragma unroll
    for (int reg = 0; reg < 4; ++reg) {
        int j = j0 + g * 4 + reg;
        size_t base = outpad ? (size_t)((i + 1) * PADW + j + 1) * H2C
                             : (size_t)(i * 100 + j) * H2C;
        Ob[base + q0 + r]      = f2bf(fmaxf(acc0[reg] + bi0, 0.f));
        Ob[base + q0 + 16 + r] = f2bf(fmaxf(acc1[reg] + bi1, 0.f));
    }
}

// ---------- q4: 1x1 conv 128->2 + sigmoid ----------
__global__ void k_q4(const float* __restrict__ w, const float* __restrict__ bias,
                     float* __restrict__ out) {
    int id = blockIdx.x * 256 + threadIdx.x;
    if (id >= BB * IJ) return;
    int b = id / IJ, ij = id % IJ;
    const unsigned short* row = (const unsigned short*)(g_buf + OFF_P3) + (size_t)id * H2C;
    float a0 = bias[0], a1 = bias[1];
    for (int c = 0; c < H2C; c += 8) {
        bf16x8 v = *(const bf16x8*)(row + c);
        #pragma unroll
        for (int t = 0; t < 8; ++t) {
            float f = bf2f((unsigned short)v[t]);
            a0 = fmaf(f, w[c + t], a0);
            a1 = fmaf(f, w[128 + c + t], a1);
        }
    }
    out[(size_t)(b * 2) * IJ + ij]     = 1.f / (1.f + expf(-a0));
    out[(size_t)(b * 2 + 1) * IJ + ij] = 1.f / (1.f + expf(-a1));
}

extern "C" void kernel_launch(void* const* d_in, const int* in_sizes, int n_in,
                              void* d_out, int out_size, void* d_ws, size_t ws_size,
                              hipStream_t stream) {
    const float* x   = (const float*)d_in[0];
    const float* wb1 = (const float*)d_in[1];  const float* bb1 = (const float*)d_in[2];
    const float* wb2 = (const float*)d_in[3];  const float* bb2 = (const float*)d_in[4];
    const float* ws1 = (const float*)d_in[5];  const float* bs1 = (const float*)d_in[6];
    const float* ws2 = (const float*)d_in[7];  const float* bs2 = (const float*)d_in[8];
    const float* we1 = (const float*)d_in[9];  const float* be1 = (const float*)d_in[10];
    const float* we2 = (const float*)d_in[11]; const float* be2 = (const float*)d_in[12];
    const float* wp  = (const float*)d_in[13]; const float* bp  = (const float*)d_in[14];
    const float* w3d = (const float*)d_in[15]; const float* b3d = (const float*)d_in[16];
    const float* wq1 = (const float*)d_in[17]; const float* bq1 = (const float*)d_in[18];
    const float* wq2 = (const float*)d_in[19]; const float* bq2 = (const float*)d_in[20];
    const float* wq3 = (const float*)d_in[21]; const float* bq3 = (const float*)d_in[22];
    const float* wq4 = (const float*)d_in[23]; const float* bq4 = (const float*)d_in[24];
    float* out = (float*)d_out;

    k_wprep<<<1408, 256, 0, stream>>>(wq1, wq2, wq3);
    k_halo<<<202, 256, 0, stream>>>();
    k_desc<<<3840, 256, 0, stream>>>();
    k_w3prep<<<512, 256, 0, stream>>>(w3d);
    k_xt<<<(BB * TT * CIN + 255) / 256, 256, 0, stream>>>(x);
    k_conv_g<<<200, 256, 0, stream>>>(OFF_XT, wb1, bb1, OFF_H1, 100, 64, CIN);
    k_conv_g<<<200, 256, 0, stream>>>(OFF_H1, wb2, bb2, OFF_H2, 64, 64, H1);
    k_conv_g<<<200, 256, 0, stream>>>(OFF_H2, ws1, bs1, OFF_SB, 64, 64, H1);
    k_conv_g<<<200, 256, 0, stream>>>(OFF_H2, we1, be1, OFF_EB, 64, 64, H1);
    k_head<<<1, 256, 0, stream>>>(OFF_SB, ws2, bs2, out + 40000);
    k_head<<<1, 256, 0, stream>>>(OFF_EB, we2, be2, out + 40200);
    k_conv_g<<<200, 256, 0, stream>>>(OFF_H2, wp, bp, OFF_PF, 256, 256, H1);
    k_pfT<<<(BB * 112 * 256 + 255) / 256, 256, 0, stream>>>();
    k_Am<<<dim3(7, 4, 64), 256, 0, stream>>>();
    k_bm2<<<dim3(10, 32, 2), 256, 0, stream>>>(b3d);
    k_q1m<<<1250, 256, 0, stream>>>(bq1);
    k_c3m<<<dim3(7, 100, 2), 256, 0, stream>>>(OFF_P1, OFF_WQ2B, bq2, OFF_P2, 1);
    k_c3m<<<dim3(7, 100, 2), 256, 0, stream>>>(OFF_P2, OFF_WQ3B, bq3, OFF_P3, 0);
    k_q4<<<(BB * IJ + 255) / 256, 256, 0, stream>>>(wq4, bq4, out);
}

// Round 5
// 538.984 us; speedup vs baseline: 2.2653x; 1.1223x over previous
//
#include <hip/hip_runtime.h>
#include <hip/hip_bf16.h>
#include <math.h>

#define TT  100
#define CIN 400
#define H1  256
#define NS  32
#define NP  96
#define H3  512
#define H2C 128
#define BB  2
#define IJ  10000
#define PADW 102
#define PPIX 10432
#define PSTRIDE (PPIX * H2C)

typedef __attribute__((ext_vector_type(8))) short bf16x8;
typedef __attribute__((ext_vector_type(4))) float f32x4;

// ---- static scratch (float units) ----
#define OFF_XT   0
#define OFF_H1   80000
#define OFF_H2   131200
#define OFF_SB   182400
#define OFF_EB   233600
#define OFF_PF   284800
#define OFF_ATB  336000      // bf16 ATb[b][64][3200][8] = 3,276,800 ush = 1,638,400 fl
#define OFF_CM2T 3612800     // bf16 [b][ij][512] = 5,120,000 fl
#define OFF_P1   8732800
#define OFF_P2   10068096
#define OFF_P3   11403392
#define OFF_WQ1B 12683392
#define OFF_WQ2B 12716160
#define OFF_WQ3B 12789888
#define OFF_DESC 12863616    // u32 [96][10240] = 983,040 fl
#define OFF_PFT  13846656    // bf16 [b][112][256] = 28,672 fl
#define OFF_W3B  13875328    // bf16 [n][o][c] 32*512*256 = 2,097,152 fl
#define G_TOTAL  15972480

__device__ __align__(16) float g_buf[G_TOTAL];

__device__ inline unsigned short f2bf(float f) {
    __hip_bfloat16 h = __float2bfloat16(f);
    return *(unsigned short*)&h;
}
__device__ inline float bf2f(unsigned short u) {
    union { unsigned int i; float f; } v; v.i = ((unsigned int)u) << 16; return v.f;
}

// ---------- transpose x: (B,T,C) -> (B,C,T) ----------
__global__ void k_xt(const float* __restrict__ x) {
    int id = blockIdx.x * 256 + threadIdx.x;
    if (id >= BB * TT * CIN) return;
    int c = id % CIN, t = (id / CIN) % TT, b = id / (CIN * TT);
    g_buf[OFF_XT + (b * CIN + c) * TT + t] = x[id];
}

// ---------- generic conv1d k=3 pad=1 + relu ----------
__global__ void k_conv_g(int in_off, const float* __restrict__ w,
                         const float* __restrict__ bias, int out_off,
                         int ipg, int opg, int cinTot) {
    int id = blockIdx.x * 256 + threadIdx.x;
    if (id >= BB * H1 * TT) return;
    int t = id % TT, o = (id / TT) % H1, b = id / (TT * H1);
    const float* ip = g_buf + in_off + (b * cinTot + (o / opg) * ipg) * TT + t;
    const float* wp = w + o * ipg * 3;
    float acc = bias[o];
    for (int ci = 0; ci < ipg; ++ci) {
        float v0 = (t > 0)      ? ip[ci * TT - 1] : 0.f;
        float v1 = ip[ci * TT];
        float v2 = (t < TT - 1) ? ip[ci * TT + 1] : 0.f;
        acc = fmaf(v0, wp[ci * 3 + 0], acc);
        acc = fmaf(v1, wp[ci * 3 + 1], acc);
        acc = fmaf(v2, wp[ci * 3 + 2], acc);
    }
    g_buf[out_off + id] = fmaxf(acc, 0.f);
}

// ---------- 1x1 head: sigmoid ----------
__global__ void k_head(int in_off, const float* __restrict__ w,
                       const float* __restrict__ bias, float* __restrict__ out) {
    int id = threadIdx.x;
    if (id >= BB * TT) return;
    int t = id % TT, b = id / TT;
    const float* ip = g_buf + in_off + b * H1 * TT + t;
    float acc = bias[0];
    for (int c = 0; c < H1; ++c) acc = fmaf(ip[c * TT], w[c], acc);
    out[id] = 1.f / (1.f + expf(-acc));
}

// ---------- pfT[b][t(112 pad)][c] bf16 from pf[b][c][t] ----------
__global__ void k_pfT() {
    int id = blockIdx.x * 256 + threadIdx.x;   // 2*112*256
    if (id >= BB * 112 * 256) return;
    int c = id & 255, t = (id >> 8) % 112, b = id / (112 * 256);
    unsigned short* pfT = (unsigned short*)(g_buf + OFF_PFT);
    float v = (t < TT) ? g_buf[OFF_PF + (b * H1 + c) * TT + t] : 0.f;
    pfT[id] = f2bf(v);
}

// ---------- w3b[n][o][c] bf16 from w3d[o][c][n], LDS transpose per o ----------
__global__ __launch_bounds__(256) void k_w3prep(const float* __restrict__ w3d) {
    __shared__ float tile[8192];
    int o = blockIdx.x, tid = threadIdx.x;
    const float* src = w3d + o * 8192;         // [c][n] contiguous for fixed o
    for (int idx = tid; idx < 8192; idx += 256) tile[idx] = src[idx];
    __syncthreads();
    int n = tid & 31, ch = tid >> 5;           // ch: chunk of 32 c
    unsigned short* w3b = (unsigned short*)(g_buf + OFF_W3B);
    unsigned int w[16];
    #pragma unroll
    for (int c2 = 0; c2 < 16; ++c2) {
        int c = ch * 32 + c2 * 2;
        w[c2] = (unsigned int)f2bf(tile[c * 32 + n]) |
                ((unsigned int)f2bf(tile[(c + 1) * 32 + n]) << 16);
    }
    uint4* dst = (uint4*)(w3b + ((size_t)n * 512 + o) * 256 + ch * 32);
    dst[0] = make_uint4(w[0], w[1], w[2], w[3]);
    dst[1] = make_uint4(w[4], w[5], w[6], w[7]);
    dst[2] = make_uint4(w[8], w[9], w[10], w[11]);
    dst[3] = make_uint4(w[12], w[13], w[14], w[15]);
}

// ---------- ATb[b][o>>3][n*100+t][o&7] = (1/3)*sum_c pf*w3d  (MFMA, bf16) ----------
__global__ __launch_bounds__(256) void k_Am() {
    int mt = blockIdx.x, nt = blockIdx.y, bn = blockIdx.z;
    int b = bn >> 5, n = bn & 31;
    int wv = threadIdx.x >> 6, lane = threadIdx.x & 63;
    int r = lane & 15, g = lane >> 4;
    const unsigned short* ap = (const unsigned short*)(g_buf + OFF_PFT)
                               + ((size_t)b * 112 + mt * 16 + r) * 256 + g * 8;
    const unsigned short* bp = (const unsigned short*)(g_buf + OFF_W3B)
                               + ((size_t)n * 512 + nt * 128 + wv * 32 + r) * 256 + g * 8;
    f32x4 acc0 = {0.f, 0.f, 0.f, 0.f}, acc1 = {0.f, 0.f, 0.f, 0.f};
    #pragma unroll
    for (int ks = 0; ks < 8; ++ks) {
        bf16x8 a  = *(const bf16x8*)(ap + ks * 32);
        bf16x8 b0 = *(const bf16x8*)(bp + ks * 32);
        bf16x8 b1 = *(const bf16x8*)(bp + 16 * 256 + ks * 32);
        acc0 = __builtin_amdgcn_mfma_f32_16x16x32_bf16(a, b0, acc0, 0, 0, 0);
        acc1 = __builtin_amdgcn_mfma_f32_16x16x32_bf16(a, b1, acc1, 0, 0, 0);
    }
    unsigned short* ATb = (unsigned short*)(g_buf + OFF_ATB);
    int o0 = nt * 128 + wv * 32 + r, o1 = o0 + 16;
    #pragma unroll
    for (int reg = 0; reg < 4; ++reg) {
        int t = mt * 16 + g * 4 + reg;
        if (t < TT) {
            size_t m = (size_t)(n * 100 + t);
            ATb[((size_t)(b * 64 + (o0 >> 3)) * 3200 + m) * 8 + (o0 & 7)] =
                f2bf(acc0[reg] * (1.f / 3.f));
            ATb[((size_t)(b * 64 + (o1 >> 3)) * 3200 + m) * 8 + (o1 & 7)] =
                f2bf(acc1[reg] * (1.f / 3.f));
        }
    }
}

// ---------- desc[k][q]: exact f64 sample math, once per (ij,k) ----------
__global__ void k_desc() {
    int id = blockIdx.x * 256 + threadIdx.x;   // 96*10240
    if (id >= NP * 10240) return;
    int k = id / 10240, q = id - k * 10240;
    int i = q / 100, j = q - i * 100;
    unsigned int nb = (unsigned int)((k / 3) * 100);
    unsigned int d;
    if (q >= IJ || i > j) {
        d = nb | (2u << 12);
    } else {
        double len = (double)(j - i + 2);
        double xmn = (double)i - 0.5 * len;
        double xmx = (double)(j + 1) + 0.5 * len;
        double plen = (xmx - xmn) / 95.0;
        double s = __dadd_rn(xmn, __dmul_rn(plen, (double)k));
        double tr = trunc(s);
        double dec = s - tr;
        int dn = (int)tr;
        int up = (int)ceil(s);
        bool okd = (unsigned)dn < (unsigned)TT;
        bool oku = (unsigned)up < (unsigned)TT;
        if (!okd) d = nb | (2u << 12);
        else if (oku && up == dn + 1) {
            unsigned int dfx = (unsigned int)__double2int_rn(dec * 65535.0);
            d = (nb + dn) | (dfx << 16);                       // mode 0: two taps
        } else if (oku) {                                       // up==dn: w = 1/3
            d = (nb + dn) | (1u << 12);
        } else {                                                // dn=99, s in (99,100)
            unsigned int dfx = (unsigned int)__double2int_rn(dec * 65535.0);
            d = (nb + dn) | (1u << 12) | (dfx << 16);           // mode 1: w=(1-dec)/3
        }
    }
    ((unsigned int*)(g_buf + OFF_DESC))[id] = d;
}

// ---------- BM gather (bf16, 8 ch/block) + conv3d bias/relu ----------
__global__ __launch_bounds__(256) void k_bm2(const float* __restrict__ b3d) {
    __shared__ unsigned short Ash[800 * 8];    // 12.8 KB, row slot = t ^ ((t>>3)&7)
    int tij = blockIdx.x, og = blockIdx.y, b = blockIdx.z;
    int tid = threadIdx.x;
    int q0 = tij * 1024 + tid;
    const unsigned int* desc = (const unsigned int*)(g_buf + OFF_DESC);
    const uint4* src = (const uint4*)((const unsigned short*)(g_buf + OFF_ATB)
                                      + (size_t)(b * 64 + og) * 3200 * 8);
    float acc[4][8];
    #pragma unroll
    for (int u = 0; u < 4; ++u)
        #pragma unroll
        for (int c = 0; c < 8; ++c) acc[u][c] = 0.f;

    for (int st = 0; st < 4; ++st) {
        __syncthreads();
        for (int idx = tid; idx < 800; idx += 256) {
            int slot = idx ^ ((idx >> 3) & 7);
            ((uint4*)Ash)[slot] = src[st * 800 + idx];
        }
        __syncthreads();
        for (int kk = 0; kk < 24; ++kk) {
            const unsigned int* dk = desc + (size_t)(st * 24 + kk) * 10240 + q0;
            #pragma unroll
            for (int u = 0; u < 4; ++u) {
                unsigned int d = dk[u * 256];
                int t = (int)(d & 0xFFFu) - st * 800;
                int mode = (d >> 12) & 3;
                float dec = (float)(d >> 16) * (1.f / 65535.f);
                float w0 = (mode == 2) ? 0.f : 1.f - dec;     // 1/3 folded into ATb
                float w1 = (mode == 0) ? dec : 0.f;
                int t1 = (mode == 0) ? t + 1 : t;
                int s0 = t ^ ((t >> 3) & 7);
                int s1 = t1 ^ ((t1 >> 3) & 7);
                bf16x8 a0 = *(const bf16x8*)(Ash + s0 * 8);
                bf16x8 a1 = *(const bf16x8*)(Ash + s1 * 8);
                #pragma unroll
                for (int c = 0; c < 8; ++c)
                    acc[u][c] = fmaf(w0, bf2f((unsigned short)a0[c]),
                               fmaf(w1, bf2f((unsigned short)a1[c]), acc[u][c]));
            }
        }
    }
    unsigned short* cm2T = (unsigned short*)(g_buf + OFF_CM2T);
    #pragma unroll
    for (int u = 0; u < 4; ++u) {
        int q = q0 + u * 256 - tid + tid;      // q0 already includes tid
        q = tij * 1024 + u * 256 + tid;
        if (q < IJ) {
            unsigned int w[4];
            #pragma unroll
            for (int c2 = 0; c2 < 4; ++c2) {
                float v0 = fmaxf(acc[u][c2 * 2]     + b3d[og * 8 + c2 * 2],     0.f);
                float v1 = fmaxf(acc[u][c2 * 2 + 1] + b3d[og * 8 + c2 * 2 + 1], 0.f);
                w[c2] = (unsigned int)f2bf(v0) | ((unsigned int)f2bf(v1) << 16);
            }
            *(uint4*)(cm2T + ((size_t)b * IJ + q) * 512 + og * 8) =
                make_uint4(w[0], w[1], w[2], w[3]);
        }
    }
}

// ---------- weight prep for 2D head ----------
__global__ void k_wprep(const float* __restrict__ wq1, const float* __restrict__ wq2,
                        const float* __restrict__ wq3) {
    int id = blockIdx.x * 256 + threadIdx.x;
    unsigned short* w1 = (unsigned short*)(g_buf + OFF_WQ1B);
    unsigned short* w2 = (unsigned short*)(g_buf + OFF_WQ2B);
    unsigned short* w3 = (unsigned short*)(g_buf + OFF_WQ3B);
    if (id < 65536) { w1[id] = f2bf(wq1[id]); return; }
    id -= 65536;
    if (id < 147456) {
        int q = id / 1152, k = id % 1152, tap = k >> 7, c = k & 127;
        w2[id] = f2bf(wq2[(q * 128 + c) * 9 + tap]); return;
    }
    id -= 147456;
    if (id < 147456) {
        int q = id / 1152, k = id % 1152, tap = k >> 7, c = k & 127;
        w3[id] = f2bf(wq3[(q * 128 + c) * 9 + tap]);
    }
}

// ---------- zero halos of P1/P2 ----------
__global__ void k_halo() {
    int id = blockIdx.x * 256 + threadIdx.x;
    if (id >= 51712) return;
    int c = id & 31;
    int h = (id >> 5) % 404;
    int bb = ((id >> 5) / 404) & 1;
    int buf = id / 25856;
    int pix;
    if (h < 102) pix = h;
    else if (h < 204) pix = 101 * PADW + (h - 102);
    else { int q = h - 204; pix = (1 + (q >> 1)) * PADW + ((q & 1) ? 101 : 0); }
    unsigned short* P = (unsigned short*)(g_buf + (buf ? OFF_P2 : OFF_P1))
                        + (size_t)bb * PSTRIDE + (size_t)pix * H2C;
    ((uint2*)P)[c] = make_uint2(0u, 0u);
}

// ---------- q1: 1x1 conv 512->128, MFMA ----------
__global__ __launch_bounds__(256) void k_q1m(const float* __restrict__ bias) {
    const unsigned short* A  = (const unsigned short*)(g_buf + OFF_CM2T);
    const unsigned short* Bw = (const unsigned short*)(g_buf + OFF_WQ1B);
    unsigned short* P1 = (unsigned short*)(g_buf + OFF_P1);
    int m0 = blockIdx.x * 16;
    int wv = threadIdx.x >> 6, lane = threadIdx.x & 63;
    int r = lane & 15, g = lane >> 4;
    int q0 = wv * 32;
    const unsigned short* arow  = A  + (size_t)(m0 + r) * 512 + g * 8;
    const unsigned short* b0row = Bw + (size_t)(q0 + r) * 512 + g * 8;
    const unsigned short* b1row = Bw + (size_t)(q0 + 16 + r) * 512 + g * 8;
    f32x4 acc0 = {0.f, 0.f, 0.f, 0.f}, acc1 = {0.f, 0.f, 0.f, 0.f};
    #pragma unroll 4
    for (int ks = 0; ks < 16; ++ks) {
        bf16x8 a  = *(const bf16x8*)(arow  + ks * 32);
        bf16x8 b0 = *(const bf16x8*)(b0row + ks * 32);
        bf16x8 b1 = *(const bf16x8*)(b1row + ks * 32);
        acc0 = __builtin_amdgcn_mfma_f32_16x16x32_bf16(a, b0, acc0, 0, 0, 0);
        acc1 = __builtin_amdgcn_mfma_f32_16x16x32_bf16(a, b1, acc1, 0, 0, 0);
    }
    int bb = m0 / IJ;
    unsigned short* Pout = P1 + (size_t)bb * PSTRIDE;
    float bi0 = bias[q0 + r], bi1 = bias[q0 + 16 + r];
    #pragma unroll
    for (int reg = 0; reg < 4; ++reg) {
        int p = m0 + g * 4 + reg;
        int ij = p - bb * IJ;
        int i = ij / 100, j = ij - i * 100;
        size_t base = (size_t)((i + 1) * PADW + j + 1) * H2C;
        Pout[base + q0 + r]      = f2bf(fmaxf(acc0[reg] + bi0, 0.f));
        Pout[base + q0 + 16 + r] = f2bf(fmaxf(acc1[reg] + bi1, 0.f));
    }
}

// ---------- 3x3 conv 128->128, MFMA implicit GEMM ----------
__global__ __launch_bounds__(256) void k_c3m(int in_off, int w_off,
                                             const float* __restrict__ bias,
                                             int out_off, int outpad) {
    const unsigned short* Pin = (const unsigned short*)(g_buf + in_off);
    const unsigned short* wB  = (const unsigned short*)(g_buf + w_off);
    unsigned short* Pout = (unsigned short*)(g_buf + out_off);
    int jt = blockIdx.x, i = blockIdx.y, b = blockIdx.z;
    int j0 = (jt == 6) ? 84 : jt * 16;
    int wv = threadIdx.x >> 6, lane = threadIdx.x & 63;
    int r = lane & 15, g = lane >> 4;
    int q0 = wv * 32;
    const unsigned short* Ab = Pin + (size_t)b * PSTRIDE;
    f32x4 acc0 = {0.f, 0.f, 0.f, 0.f}, acc1 = {0.f, 0.f, 0.f, 0.f};
    #pragma unroll 1
    for (int ky = 0; ky < 3; ++ky) {
        #pragma unroll
        for (int kx = 0; kx < 3; ++kx) {
            int tap = ky * 3 + kx;
            const unsigned short* arow = Ab + (size_t)((i + ky) * PADW + j0 + r + kx) * H2C + g * 8;
            const unsigned short* b0r = wB + (size_t)(q0 + r) * 1152 + tap * 128 + g * 8;
            const unsigned short* b1r = wB + (size_t)(q0 + 16 + r) * 1152 + tap * 128 + g * 8;
            #pragma unroll
            for (int cc = 0; cc < 4; ++cc) {
                bf16x8 a  = *(const bf16x8*)(arow + cc * 32);
                bf16x8 b0 = *(const bf16x8*)(b0r + cc * 32);
                bf16x8 b1 = *(const bf16x8*)(b1r + cc * 32);
                acc0 = __builtin_amdgcn_mfma_f32_16x16x32_bf16(a, b0, acc0, 0, 0, 0);
                acc1 = __builtin_amdgcn_mfma_f32_16x16x32_bf16(a, b1, acc1, 0, 0, 0);
            }
        }
    }
    float bi0 = bias[q0 + r], bi1 = bias[q0 + 16 + r];
    unsigned short* Ob = Pout + (size_t)b * (outpad ? (size_t)PSTRIDE : (size_t)IJ * H2C);
    #pragma unroll
    for (int reg = 0; reg < 4; ++reg) {
        int j = j0 + g * 4 + reg;
        size_t base = outpad ? (size_t)((i + 1) * PADW + j + 1) * H2C
                             : (size_t)(i * 100 + j) * H2C;
        Ob[base + q0 + r]      = f2bf(fmaxf(acc0[reg] + bi0, 0.f));
        Ob[base + q0 + 16 + r] = f2bf(fmaxf(acc1[reg] + bi1, 0.f));
    }
}

// ---------- q4: 1x1 conv 128->2 + sigmoid ----------
__global__ void k_q4(const float* __restrict__ w, const float* __restrict__ bias,
                     float* __restrict__ out) {
    int id = blockIdx.x * 256 + threadIdx.x;
    if (id >= BB * IJ) return;
    int b = id / IJ, ij = id % IJ;
    const unsigned short* row = (const unsigned short*)(g_buf + OFF_P3) + (size_t)id * H2C;
    float a0 = bias[0], a1 = bias[1];
    for (int c = 0; c < H2C; c += 8) {
        bf16x8 v = *(const bf16x8*)(row + c);
        #pragma unroll
        for (int t = 0; t < 8; ++t) {
            float f = bf2f((unsigned short)v[t]);
            a0 = fmaf(f, w[c + t], a0);
            a1 = fmaf(f, w[128 + c + t], a1);
        }
    }
    out[(size_t)(b * 2) * IJ + ij]     = 1.f / (1.f + expf(-a0));
    out[(size_t)(b * 2 + 1) * IJ + ij] = 1.f / (1.f + expf(-a1));
}

extern "C" void kernel_launch(void* const* d_in, const int* in_sizes, int n_in,
                              void* d_out, int out_size, void* d_ws, size_t ws_size,
                              hipStream_t stream) {
    const float* x   = (const float*)d_in[0];
    const float* wb1 = (const float*)d_in[1];  const float* bb1 = (const float*)d_in[2];
    const float* wb2 = (const float*)d_in[3];  const float* bb2 = (const float*)d_in[4];
    const float* ws1 = (const float*)d_in[5];  const float* bs1 = (const float*)d_in[6];
    const float* ws2 = (const float*)d_in[7];  const float* bs2 = (const float*)d_in[8];
    const float* we1 = (const float*)d_in[9];  const float* be1 = (const float*)d_in[10];
    const float* we2 = (const float*)d_in[11]; const float* be2 = (const float*)d_in[12];
    const float* wp  = (const float*)d_in[13]; const float* bp  = (const float*)d_in[14];
    const float* w3d = (const float*)d_in[15]; const float* b3d = (const float*)d_in[16];
    const float* wq1 = (const float*)d_in[17]; const float* bq1 = (const float*)d_in[18];
    const float* wq2 = (const float*)d_in[19]; const float* bq2 = (const float*)d_in[20];
    const float* wq3 = (const float*)d_in[21]; const float* bq3 = (const float*)d_in[22];
    const float* wq4 = (const float*)d_in[23]; const float* bq4 = (const float*)d_in[24];
    float* out = (float*)d_out;

    k_wprep<<<1408, 256, 0, stream>>>(wq1, wq2, wq3);
    k_halo<<<202, 256, 0, stream>>>();
    k_desc<<<3840, 256, 0, stream>>>();
    k_w3prep<<<512, 256, 0, stream>>>(w3d);
    k_xt<<<(BB * TT * CIN + 255) / 256, 256, 0, stream>>>(x);
    k_conv_g<<<200, 256, 0, stream>>>(OFF_XT, wb1, bb1, OFF_H1, 100, 64, CIN);
    k_conv_g<<<200, 256, 0, stream>>>(OFF_H1, wb2, bb2, OFF_H2, 64, 64, H1);
    k_conv_g<<<200, 256, 0, stream>>>(OFF_H2, ws1, bs1, OFF_SB, 64, 64, H1);
    k_conv_g<<<200, 256, 0, stream>>>(OFF_H2, we1, be1, OFF_EB, 64, 64, H1);
    k_head<<<1, 256, 0, stream>>>(OFF_SB, ws2, bs2, out + 40000);
    k_head<<<1, 256, 0, stream>>>(OFF_EB, we2, be2, out + 40200);
    k_conv_g<<<200, 256, 0, stream>>>(OFF_H2, wp, bp, OFF_PF, 256, 256, H1);
    k_pfT<<<(BB * 112 * 256 + 255) / 256, 256, 0, stream>>>();
    k_Am<<<dim3(7, 4, 64), 256, 0, stream>>>();
    k_bm2<<<dim3(10, 64, 2), 256, 0, stream>>>(b3d);
    k_q1m<<<1250, 256, 0, stream>>>(bq1);
    k_c3m<<<dim3(7, 100, 2), 256, 0, stream>>>(OFF_P1, OFF_WQ2B, bq2, OFF_P2, 1);
    k_c3m<<<dim3(7, 100, 2), 256, 0, stream>>>(OFF_P2, OFF_WQ3B, bq3, OFF_P3, 0);
    k_q4<<<(BB * IJ + 255) / 256, 256, 0, stream>>>(wq4, bq4, out);
}

// Round 6
// 414.229 us; speedup vs baseline: 2.9475x; 1.3012x over previous
//
#include <hip/hip_runtime.h>
#include <hip/hip_bf16.h>
#include <math.h>

#define TT  100
#define CIN 400
#define H1  256
#define NS  32
#define NP  96
#define H3  512
#define H2C 128
#define BB  2
#define IJ  10000
#define PADW 102
#define PPIX 10432
#define PSTRIDE (PPIX * H2C)

typedef __attribute__((ext_vector_type(8))) short bf16x8;
typedef __attribute__((ext_vector_type(4))) float f32x4;

// ---- static scratch (float units) ----
#define OFF_XT   0
#define OFF_H1   80000
#define OFF_H2   131200
#define OFF_SB   182400
#define OFF_EB   233600
#define OFF_PF   284800
#define OFF_ATB  336000      // bf16 pairs ATb2[b][64][3200][8][2] = 6,553,600 ush = 3,276,800 fl
#define OFF_CM2T 3612800     // bf16 [b][ij][512] = 5,120,000 fl
#define OFF_P1   8732800
#define OFF_P2   10068096
#define OFF_P3   11403392
#define OFF_WQ1B 12683392
#define OFF_WQ2B 12716160
#define OFF_WQ3B 12789888
#define OFF_DESC 12863616    // u32 [96][10240] = 983,040 fl
#define OFF_PFT  13846656    // bf16 [b][112][256] = 28,672 fl
#define OFF_W3B  13875328    // bf16 [n][o][c] 32*512*256 = 2,097,152 fl
#define G_TOTAL  15972480

__device__ __align__(16) float g_buf[G_TOTAL];

__device__ inline unsigned short f2bf(float f) {
    __hip_bfloat16 h = __float2bfloat16(f);
    return *(unsigned short*)&h;
}
__device__ inline float bf2f(unsigned short u) {
    union { unsigned int i; float f; } v; v.i = ((unsigned int)u) << 16; return v.f;
}
// acc += lo(a)*lo(w) + hi(a)*hi(w), all bf16 inputs, f32 accum
__device__ inline void dot2(float& acc, unsigned int a, unsigned int w) {
    asm("v_dot2_f32_bf16 %0, %1, %2, %0" : "+v"(acc) : "v"(a), "v"(w));
}

// ---------- merged prep: wq1/wq2/wq3 bf16-prep + halo zero + desc + x transpose ----------
__global__ void k_prep(const float* __restrict__ wq1, const float* __restrict__ wq2,
                       const float* __restrict__ wq3, const float* __restrict__ x) {
    int id = blockIdx.x * 256 + threadIdx.x;
    if (id < 65536) {
        ((unsigned short*)(g_buf + OFF_WQ1B))[id] = f2bf(wq1[id]);
        return;
    }
    id -= 65536;
    if (id < 147456) {
        int q = id / 1152, k = id % 1152, tap = k >> 7, c = k & 127;
        ((unsigned short*)(g_buf + OFF_WQ2B))[id] = f2bf(wq2[(q * 128 + c) * 9 + tap]);
        return;
    }
    id -= 147456;
    if (id < 147456) {
        int q = id / 1152, k = id % 1152, tap = k >> 7, c = k & 127;
        ((unsigned short*)(g_buf + OFF_WQ3B))[id] = f2bf(wq3[(q * 128 + c) * 9 + tap]);
        return;
    }
    id -= 147456;
    if (id < 51712) {   // halo zero
        int c = id & 31;
        int h = (id >> 5) % 404;
        int bb = ((id >> 5) / 404) & 1;
        int buf = id / 25856;
        int pix;
        if (h < 102) pix = h;
        else if (h < 204) pix = 101 * PADW + (h - 102);
        else { int q = h - 204; pix = (1 + (q >> 1)) * PADW + ((q & 1) ? 101 : 0); }
        unsigned short* P = (unsigned short*)(g_buf + (buf ? OFF_P2 : OFF_P1))
                            + (size_t)bb * PSTRIDE + (size_t)pix * H2C;
        ((uint2*)P)[c] = make_uint2(0u, 0u);
        return;
    }
    id -= 51712;
    if (id < NP * 10240) {   // desc: exact f64 sample math once per (ij,k)
        int k = id / 10240, q = id - k * 10240;
        int i = q / 100, j = q - i * 100;
        unsigned int nb = (unsigned int)((k / 3) * 100);
        unsigned int d;
        if (q >= IJ || i > j) {
            d = nb | (2u << 12);
        } else {
            double len = (double)(j - i + 2);
            double xmn = (double)i - 0.5 * len;
            double xmx = (double)(j + 1) + 0.5 * len;
            double plen = (xmx - xmn) / 95.0;
            double s = __dadd_rn(xmn, __dmul_rn(plen, (double)k));
            double tr = trunc(s);
            double dec = s - tr;
            int dn = (int)tr;
            int up = (int)ceil(s);
            bool okd = (unsigned)dn < (unsigned)TT;
            bool oku = (unsigned)up < (unsigned)TT;
            if (!okd) d = nb | (2u << 12);
            else if (oku && up == dn + 1) {
                unsigned int dfx = (unsigned int)__double2int_rn(dec * 65535.0);
                d = (nb + dn) | (dfx << 16);                 // mode 0: two taps
            } else if (oku) {                                 // up==dn: w=1/3 (dec=0)
                d = (nb + dn) | (1u << 12);
            } else {                                          // dn=99, s in (99,100)
                unsigned int dfx = (unsigned int)__double2int_rn(dec * 65535.0);
                d = (nb + dn) | (1u << 12) | (dfx << 16);     // mode 1: w=(1-dec)/3
            }
        }
        ((unsigned int*)(g_buf + OFF_DESC))[id] = d;
        return;
    }
    id -= NP * 10240;
    if (id < BB * TT * CIN) {   // x transpose
        int c = id % CIN, t = (id / CIN) % TT, b = id / (CIN * TT);
        g_buf[OFF_XT + (b * CIN + c) * TT + t] = x[id];
    }
}
#define PREP_IDS (65536 + 147456 + 147456 + 51712 + NP * 10240 + BB * TT * CIN)

// ---------- conv1d k=3 pad=1 + relu, compile-time shapes for unroll/ILP ----------
template<int IPG, int OPG, int CINTOT>
__global__ void k_conv_t(int in_off, const float* __restrict__ w,
                         const float* __restrict__ bias, int out_off) {
    int id = blockIdx.x * 256 + threadIdx.x;
    if (id >= BB * H1 * TT) return;
    int t = id % TT, o = (id / TT) % H1, b = id / (TT * H1);
    const float* ip = g_buf + in_off + (b * CINTOT + (o / OPG) * IPG) * TT + t;
    const float* wp = w + o * IPG * 3;
    float acc = bias[o];
    bool t0 = (t > 0), t1 = (t < TT - 1);
    #pragma unroll 4
    for (int ci = 0; ci < IPG; ++ci) {
        float v0 = t0 ? ip[ci * TT - 1] : 0.f;
        float v1 = ip[ci * TT];
        float v2 = t1 ? ip[ci * TT + 1] : 0.f;
        acc = fmaf(v0, wp[ci * 3 + 0], acc);
        acc = fmaf(v1, wp[ci * 3 + 1], acc);
        acc = fmaf(v2, wp[ci * 3 + 2], acc);
    }
    g_buf[out_off + id] = fmaxf(acc, 0.f);
}

// ---------- both 1x1 sigmoid heads in one launch ----------
__global__ void k_heads(const float* __restrict__ ws2, const float* __restrict__ bs2,
                        const float* __restrict__ we2, const float* __restrict__ be2,
                        float* __restrict__ out) {
    int which = blockIdx.x;
    const float* w  = which ? we2 : ws2;
    const float* bi = which ? be2 : bs2;
    int in_off = which ? OFF_EB : OFF_SB;
    int id = threadIdx.x;
    if (id >= BB * TT) return;
    int t = id % TT, b = id / TT;
    const float* ip = g_buf + in_off + b * H1 * TT + t;
    float acc = bi[0];
    for (int c = 0; c < H1; ++c) acc = fmaf(ip[c * TT], w[c], acc);
    out[40000 + which * 200 + id] = 1.f / (1.f + expf(-acc));
}

// ---------- pfT[b][t(112 pad)][c] bf16 from pf[b][c][t] ----------
__global__ void k_pfT() {
    int id = blockIdx.x * 256 + threadIdx.x;
    if (id >= BB * 112 * 256) return;
    int c = id & 255, t = (id >> 8) % 112, b = id / (112 * 256);
    unsigned short* pfT = (unsigned short*)(g_buf + OFF_PFT);
    float v = (t < TT) ? g_buf[OFF_PF + (b * H1 + c) * TT + t] : 0.f;
    pfT[id] = f2bf(v);
}

// ---------- w3b[n][o][c] bf16 from w3d[o][c][n], LDS transpose per o ----------
__global__ __launch_bounds__(256) void k_w3prep(const float* __restrict__ w3d) {
    __shared__ float tile[8192];
    int o = blockIdx.x, tid = threadIdx.x;
    const float* src = w3d + o * 8192;
    for (int idx = tid; idx < 8192; idx += 256) tile[idx] = src[idx];
    __syncthreads();
    int n = tid & 31, ch = tid >> 5;
    unsigned short* w3b = (unsigned short*)(g_buf + OFF_W3B);
    unsigned int w[16];
    #pragma unroll
    for (int c2 = 0; c2 < 16; ++c2) {
        int c = ch * 32 + c2 * 2;
        w[c2] = (unsigned int)f2bf(tile[c * 32 + n]) |
                ((unsigned int)f2bf(tile[(c + 1) * 32 + n]) << 16);
    }
    uint4* dst = (uint4*)(w3b + ((size_t)n * 512 + o) * 256 + ch * 32);
    dst[0] = make_uint4(w[0], w[1], w[2], w[3]);
    dst[1] = make_uint4(w[4], w[5], w[6], w[7]);
    dst[2] = make_uint4(w[8], w[9], w[10], w[11]);
    dst[3] = make_uint4(w[12], w[13], w[14], w[15]);
}

// ---------- ATb2 pairs: [b][o>>3][m][o&7][2] = ((1/3)A[m], (1/3)A[m+1]) bf16 ----------
__global__ __launch_bounds__(256) void k_Am() {
    int mt = blockIdx.x, nt = blockIdx.y, bn = blockIdx.z;
    int b = bn >> 5, n = bn & 31;
    int wv = threadIdx.x >> 6, lane = threadIdx.x & 63;
    int r = lane & 15, g = lane >> 4;
    const unsigned short* ap = (const unsigned short*)(g_buf + OFF_PFT)
                               + ((size_t)b * 112 + mt * 16 + r) * 256 + g * 8;
    const unsigned short* bp = (const unsigned short*)(g_buf + OFF_W3B)
                               + ((size_t)n * 512 + nt * 128 + wv * 32 + r) * 256 + g * 8;
    f32x4 acc0 = {0.f, 0.f, 0.f, 0.f}, acc1 = {0.f, 0.f, 0.f, 0.f};
    #pragma unroll
    for (int ks = 0; ks < 8; ++ks) {
        bf16x8 a  = *(const bf16x8*)(ap + ks * 32);
        bf16x8 b0 = *(const bf16x8*)(bp + ks * 32);
        bf16x8 b1 = *(const bf16x8*)(bp + 16 * 256 + ks * 32);
        acc0 = __builtin_amdgcn_mfma_f32_16x16x32_bf16(a, b0, acc0, 0, 0, 0);
        acc1 = __builtin_amdgcn_mfma_f32_16x16x32_bf16(a, b1, acc1, 0, 0, 0);
    }
    unsigned short* ATb = (unsigned short*)(g_buf + OFF_ATB);
    int o0 = nt * 128 + wv * 32 + r, o1 = o0 + 16;
    #pragma unroll
    for (int reg = 0; reg < 4; ++reg) {
        int t = mt * 16 + g * 4 + reg;
        if (t < TT) {
            size_t m = (size_t)(n * 100 + t);
            unsigned short v0 = f2bf(acc0[reg] * (1.f / 3.f));
            unsigned short v1 = f2bf(acc1[reg] * (1.f / 3.f));
            size_t base0 = ((size_t)(b * 64 + (o0 >> 3)) * 3200 + m) * 16 + (o0 & 7) * 2;
            size_t base1 = ((size_t)(b * 64 + (o1 >> 3)) * 3200 + m) * 16 + (o1 & 7) * 2;
            ATb[base0] = v0;                       // pair-lo of row m
            ATb[base1] = v1;
            if (t > 0) {                            // pair-hi of row m-1
                ATb[base0 - 16 + 1] = v0;
                ATb[base1 - 16 + 1] = v1;
            }
            if (t == TT - 1) {                      // pair-hi of last row in bin = 0
                ATb[base0 + 1] = 0;
                ATb[base1 + 1] = 0;
            }
        }
    }
}

// ---------- BM gather: pair dot2, 8 ch/block ----------
__global__ __launch_bounds__(256) void k_bm2(const float* __restrict__ b3d) {
    __shared__ uint4 Ash[1600];                 // 25.6 KB; slot = u ^ ((u>>3)&7)
    int tij = blockIdx.x, og = blockIdx.y, b = blockIdx.z;
    int tid = threadIdx.x;
    int q0 = tij * 1024 + tid;
    const unsigned int* desc = (const unsigned int*)(g_buf + OFF_DESC);
    const uint4* src = (const uint4*)((const unsigned short*)(g_buf + OFF_ATB)
                                      + (size_t)(b * 64 + og) * 3200 * 16);
    float acc[4][8];
    #pragma unroll
    for (int u = 0; u < 4; ++u)
        #pragma unroll
        for (int c = 0; c < 8; ++c) acc[u][c] = 0.f;

    for (int st = 0; st < 4; ++st) {
        __syncthreads();
        for (int idx = tid; idx < 1600; idx += 256)
            Ash[idx ^ ((idx >> 3) & 7)] = src[st * 1600 + idx];
        __syncthreads();
        for (int kk = 0; kk < 24; ++kk) {
            const unsigned int* dk = desc + (size_t)(st * 24 + kk) * 10240 + q0;
            #pragma unroll
            for (int u = 0; u < 4; ++u) {
                unsigned int d = dk[u * 256];
                int t = (int)(d & 0xFFFu) - st * 800;
                unsigned int mode = (d >> 12) & 3u;
                float dec = (float)(d >> 16) * (1.f / 65535.f);
                float w0 = (mode == 2u) ? 0.f : 1.f - dec;
                float w1 = (mode == 0u) ? dec : 0.f;
                unsigned int wpair;
                asm("v_cvt_pk_bf16_f32 %0, %1, %2" : "=v"(wpair) : "v"(w0), "v"(w1));
                int u0 = t * 2;
                int s0 = u0 ^ ((u0 >> 3) & 7);
                uint4 A0 = Ash[s0];
                uint4 A1 = Ash[s0 ^ 1];
                dot2(acc[u][0], A0.x, wpair); dot2(acc[u][1], A0.y, wpair);
                dot2(acc[u][2], A0.z, wpair); dot2(acc[u][3], A0.w, wpair);
                dot2(acc[u][4], A1.x, wpair); dot2(acc[u][5], A1.y, wpair);
                dot2(acc[u][6], A1.z, wpair); dot2(acc[u][7], A1.w, wpair);
            }
        }
    }
    unsigned short* cm2T = (unsigned short*)(g_buf + OFF_CM2T);
    #pragma unroll
    for (int u = 0; u < 4; ++u) {
        int q = tij * 1024 + u * 256 + tid;
        if (q < IJ) {
            unsigned int w[4];
            #pragma unroll
            for (int c2 = 0; c2 < 4; ++c2) {
                float v0 = fmaxf(acc[u][c2 * 2]     + b3d[og * 8 + c2 * 2],     0.f);
                float v1 = fmaxf(acc[u][c2 * 2 + 1] + b3d[og * 8 + c2 * 2 + 1], 0.f);
                w[c2] = (unsigned int)f2bf(v0) | ((unsigned int)f2bf(v1) << 16);
            }
            *(uint4*)(cm2T + ((size_t)b * IJ + q) * 512 + og * 8) =
                make_uint4(w[0], w[1], w[2], w[3]);
        }
    }
}

// ---------- q1: 1x1 conv 512->128, MFMA ----------
__global__ __launch_bounds__(256) void k_q1m(const float* __restrict__ bias) {
    const unsigned short* A  = (const unsigned short*)(g_buf + OFF_CM2T);
    const unsigned short* Bw = (const unsigned short*)(g_buf + OFF_WQ1B);
    unsigned short* P1 = (unsigned short*)(g_buf + OFF_P1);
    int m0 = blockIdx.x * 16;
    int wv = threadIdx.x >> 6, lane = threadIdx.x & 63;
    int r = lane & 15, g = lane >> 4;
    int q0 = wv * 32;
    const unsigned short* arow  = A  + (size_t)(m0 + r) * 512 + g * 8;
    const unsigned short* b0row = Bw + (size_t)(q0 + r) * 512 + g * 8;
    const unsigned short* b1row = Bw + (size_t)(q0 + 16 + r) * 512 + g * 8;
    f32x4 acc0 = {0.f, 0.f, 0.f, 0.f}, acc1 = {0.f, 0.f, 0.f, 0.f};
    #pragma unroll 4
    for (int ks = 0; ks < 16; ++ks) {
        bf16x8 a  = *(const bf16x8*)(arow  + ks * 32);
        bf16x8 b0 = *(const bf16x8*)(b0row + ks * 32);
        bf16x8 b1 = *(const bf16x8*)(b1row + ks * 32);
        acc0 = __builtin_amdgcn_mfma_f32_16x16x32_bf16(a, b0, acc0, 0, 0, 0);
        acc1 = __builtin_amdgcn_mfma_f32_16x16x32_bf16(a, b1, acc1, 0, 0, 0);
    }
    int bb = m0 / IJ;
    unsigned short* Pout = P1 + (size_t)bb * PSTRIDE;
    float bi0 = bias[q0 + r], bi1 = bias[q0 + 16 + r];
    #pragma unroll
    for (int reg = 0; reg < 4; ++reg) {
        int p = m0 + g * 4 + reg;
        int ij = p - bb * IJ;
        int i = ij / 100, j = ij - i * 100;
        size_t base = (size_t)((i + 1) * PADW + j + 1) * H2C;
        Pout[base + q0 + r]      = f2bf(fmaxf(acc0[reg] + bi0, 0.f));
        Pout[base + q0 + 16 + r] = f2bf(fmaxf(acc1[reg] + bi1, 0.f));
    }
}

// ---------- 3x3 conv 128->128, MFMA implicit GEMM ----------
__global__ __launch_bounds__(256) void k_c3m(int in_off, int w_off,
                                             const float* __restrict__ bias,
                                             int out_off, int outpad) {
    const unsigned short* Pin = (const unsigned short*)(g_buf + in_off);
    const unsigned short* wB  = (const unsigned short*)(g_buf + w_off);
    unsigned short* Pout = (unsigned short*)(g_buf + out_off);
    int jt = blockIdx.x, i = blockIdx.y, b = blockIdx.z;
    int j0 = (jt == 6) ? 84 : jt * 16;
    int wv = threadIdx.x >> 6, lane = threadIdx.x & 63;
    int r = lane & 15, g = lane >> 4;
    int q0 = wv * 32;
    const unsigned short* Ab = Pin + (size_t)b * PSTRIDE;
    f32x4 acc0 = {0.f, 0.f, 0.f, 0.f}, acc1 = {0.f, 0.f, 0.f, 0.f};
    #pragma unroll 1
    for (int ky = 0; ky < 3; ++ky) {
        #pragma unroll
        for (int kx = 0; kx < 3; ++kx) {
            int tap = ky * 3 + kx;
            const unsigned short* arow = Ab + (size_t)((i + ky) * PADW + j0 + r + kx) * H2C + g * 8;
            const unsigned short* b0r = wB + (size_t)(q0 + r) * 1152 + tap * 128 + g * 8;
            const unsigned short* b1r = wB + (size_t)(q0 + 16 + r) * 1152 + tap * 128 + g * 8;
            #pragma unroll
            for (int cc = 0; cc < 4; ++cc) {
                bf16x8 a  = *(const bf16x8*)(arow + cc * 32);
                bf16x8 b0 = *(const bf16x8*)(b0r + cc * 32);
                bf16x8 b1 = *(const bf16x8*)(b1r + cc * 32);
                acc0 = __builtin_amdgcn_mfma_f32_16x16x32_bf16(a, b0, acc0, 0, 0, 0);
                acc1 = __builtin_amdgcn_mfma_f32_16x16x32_bf16(a, b1, acc1, 0, 0, 0);
            }
        }
    }
    float bi0 = bias[q0 + r], bi1 = bias[q0 + 16 + r];
    unsigned short* Ob = Pout + (size_t)b * (outpad ? (size_t)PSTRIDE : (size_t)IJ * H2C);
    #pragma unroll
    for (int reg = 0; reg < 4; ++reg) {
        int j = j0 + g * 4 + reg;
        size_t base = outpad ? (size_t)((i + 1) * PADW + j + 1) * H2C
                             : (size_t)(i * 100 + j) * H2C;
        Ob[base + q0 + r]      = f2bf(fmaxf(acc0[reg] + bi0, 0.f));
        Ob[base + q0 + 16 + r] = f2bf(fmaxf(acc1[reg] + bi1, 0.f));
    }
}

// ---------- q4: 1x1 conv 128->2 + sigmoid ----------
__global__ void k_q4(const float* __restrict__ w, const float* __restrict__ bias,
                     float* __restrict__ out) {
    int id = blockIdx.x * 256 + threadIdx.x;
    if (id >= BB * IJ) return;
    int b = id / IJ, ij = id % IJ;
    const unsigned short* row = (const unsigned short*)(g_buf + OFF_P3) + (size_t)id * H2C;
    float a0 = bias[0], a1 = bias[1];
    for (int c = 0; c < H2C; c += 8) {
        bf16x8 v = *(const bf16x8*)(row + c);
        #pragma unroll
        for (int t = 0; t < 8; ++t) {
            float f = bf2f((unsigned short)v[t]);
            a0 = fmaf(f, w[c + t], a0);
            a1 = fmaf(f, w[128 + c + t], a1);
        }
    }
    out[(size_t)(b * 2) * IJ + ij]     = 1.f / (1.f + expf(-a0));
    out[(size_t)(b * 2 + 1) * IJ + ij] = 1.f / (1.f + expf(-a1));
}

extern "C" void kernel_launch(void* const* d_in, const int* in_sizes, int n_in,
                              void* d_out, int out_size, void* d_ws, size_t ws_size,
                              hipStream_t stream) {
    const float* x   = (const float*)d_in[0];
    const float* wb1 = (const float*)d_in[1];  const float* bb1 = (const float*)d_in[2];
    const float* wb2 = (const float*)d_in[3];  const float* bb2 = (const float*)d_in[4];
    const float* ws1 = (const float*)d_in[5];  const float* bs1 = (const float*)d_in[6];
    const float* ws2 = (const float*)d_in[7];  const float* bs2 = (const float*)d_in[8];
    const float* we1 = (const float*)d_in[9];  const float* be1 = (const float*)d_in[10];
    const float* we2 = (const float*)d_in[11]; const float* be2 = (const float*)d_in[12];
    const float* wp  = (const float*)d_in[13]; const float* bp  = (const float*)d_in[14];
    const float* w3d = (const float*)d_in[15]; const float* b3d = (const float*)d_in[16];
    const float* wq1 = (const float*)d_in[17]; const float* bq1 = (const float*)d_in[18];
    const float* wq2 = (const float*)d_in[19]; const float* bq2 = (const float*)d_in[20];
    const float* wq3 = (const float*)d_in[21]; const float* bq3 = (const float*)d_in[22];
    const float* wq4 = (const float*)d_in[23]; const float* bq4 = (const float*)d_in[24];
    float* out = (float*)d_out;

    k_prep<<<(PREP_IDS + 255) / 256, 256, 0, stream>>>(wq1, wq2, wq3, x);
    k_w3prep<<<512, 256, 0, stream>>>(w3d);
    k_conv_t<100, 64, 400><<<200, 256, 0, stream>>>(OFF_XT, wb1, bb1, OFF_H1);
    k_conv_t<64, 64, 256><<<200, 256, 0, stream>>>(OFF_H1, wb2, bb2, OFF_H2);
    k_conv_t<64, 64, 256><<<200, 256, 0, stream>>>(OFF_H2, ws1, bs1, OFF_SB);
    k_conv_t<64, 64, 256><<<200, 256, 0, stream>>>(OFF_H2, we1, be1, OFF_EB);
    k_heads<<<2, 256, 0, stream>>>(ws2, bs2, we2, be2, out);
    k_conv_t<256, 256, 256><<<200, 256, 0, stream>>>(OFF_H2, wp, bp, OFF_PF);
    k_pfT<<<(BB * 112 * 256 + 255) / 256, 256, 0, stream>>>();
    k_Am<<<dim3(7, 4, 64), 256, 0, stream>>>();
    k_bm2<<<dim3(10, 64, 2), 256, 0, stream>>>(b3d);
    k_q1m<<<1250, 256, 0, stream>>>(bq1);
    k_c3m<<<dim3(7, 100, 2), 256, 0, stream>>>(OFF_P1, OFF_WQ2B, bq2, OFF_P2, 1);
    k_c3m<<<dim3(7, 100, 2), 256, 0, stream>>>(OFF_P2, OFF_WQ3B, bq3, OFF_P3, 0);
    k_q4<<<(BB * IJ + 255) / 256, 256, 0, stream>>>(wq4, bq4, out);
}

// Round 7
// 371.334 us; speedup vs baseline: 3.2880x; 1.1155x over previous
//
#include <hip/hip_runtime.h>
#include <hip/hip_bf16.h>
#include <math.h>

#define TT  100
#define CIN 400
#define H1  256
#define NS  32
#define NP  96
#define H3  512
#define H2C 128
#define BB  2
#define IJ  10000
#define NVALID 5050
#define PADW 102
#define PPIX 10432
#define PSTRIDE (PPIX * H2C)

typedef __attribute__((ext_vector_type(8))) short bf16x8;
typedef __attribute__((ext_vector_type(4))) float f32x4;

// ---- static scratch (float units) ----
#define OFF_XT   0
#define OFF_H1   80000
#define OFF_H2   131200
#define OFF_SB   182400
#define OFF_EB   233600
#define OFF_PF   284800
#define OFF_ATB  336000      // bf16 pairs ATb2[b][64][3200][8][2] = 6,553,600 ush
#define OFF_CM2T 3612800     // bf16 [b][ij][512]
#define OFF_P1   8732800
#define OFF_P2   10068096
#define OFF_P3   11403392
#define OFF_WQ1B 12683392
#define OFF_WQ2B 12716160
#define OFF_WQ3B 12789888
#define OFF_DESC 12863616    // u32 [96][10240]
#define OFF_PFT  13846656    // bf16 [b][112][256]
#define OFF_W3B  13875328    // bf16 [n][o][c] 32*512*256
#define G_TOTAL  15972480

__device__ __align__(16) float g_buf[G_TOTAL];

__device__ inline unsigned short f2bf(float f) {
    __hip_bfloat16 h = __float2bfloat16(f);
    return *(unsigned short*)&h;
}
__device__ inline float bf2f(unsigned short u) {
    union { unsigned int i; float f; } v; v.i = ((unsigned int)u) << 16; return v.f;
}
__device__ inline void dot2(float& acc, unsigned int a, unsigned int w) {
    asm("v_dot2_f32_bf16 %0, %1, %2, %0" : "+v"(acc) : "v"(a), "v"(w));
}

// ---------- merged prep ----------
__global__ void k_prep(const float* __restrict__ wq1, const float* __restrict__ wq2,
                       const float* __restrict__ wq3, const float* __restrict__ x) {
    int id = blockIdx.x * 256 + threadIdx.x;
    if (id < 65536) {
        ((unsigned short*)(g_buf + OFF_WQ1B))[id] = f2bf(wq1[id]);
        return;
    }
    id -= 65536;
    if (id < 147456) {
        int q = id / 1152, k = id % 1152, tap = k >> 7, c = k & 127;
        ((unsigned short*)(g_buf + OFF_WQ2B))[id] = f2bf(wq2[(q * 128 + c) * 9 + tap]);
        return;
    }
    id -= 147456;
    if (id < 147456) {
        int q = id / 1152, k = id % 1152, tap = k >> 7, c = k & 127;
        ((unsigned short*)(g_buf + OFF_WQ3B))[id] = f2bf(wq3[(q * 128 + c) * 9 + tap]);
        return;
    }
    id -= 147456;
    if (id < 51712) {   // halo zero
        int c = id & 31;
        int h = (id >> 5) % 404;
        int bb = ((id >> 5) / 404) & 1;
        int buf = id / 25856;
        int pix;
        if (h < 102) pix = h;
        else if (h < 204) pix = 101 * PADW + (h - 102);
        else { int q = h - 204; pix = (1 + (q >> 1)) * PADW + ((q & 1) ? 101 : 0); }
        unsigned short* P = (unsigned short*)(g_buf + (buf ? OFF_P2 : OFF_P1))
                            + (size_t)bb * PSTRIDE + (size_t)pix * H2C;
        ((uint2*)P)[c] = make_uint2(0u, 0u);
        return;
    }
    id -= 51712;
    if (id < NP * 10240) {   // desc: exact f64 sample math once per (ij,k)
        int k = id / 10240, q = id - k * 10240;
        int i = q / 100, j = q - i * 100;
        unsigned int nb = (unsigned int)((k / 3) * 100);
        unsigned int d;
        if (q >= IJ || i > j) {
            d = nb | (2u << 12);
        } else {
            double len = (double)(j - i + 2);
            double xmn = (double)i - 0.5 * len;
            double xmx = (double)(j + 1) + 0.5 * len;
            double plen = (xmx - xmn) / 95.0;
            double s = __dadd_rn(xmn, __dmul_rn(plen, (double)k));
            double tr = trunc(s);
            double dec = s - tr;
            int dn = (int)tr;
            int up = (int)ceil(s);
            bool okd = (unsigned)dn < (unsigned)TT;
            bool oku = (unsigned)up < (unsigned)TT;
            if (!okd) d = nb | (2u << 12);
            else if (oku && up == dn + 1) {
                unsigned int dfx = (unsigned int)__double2int_rn(dec * 65535.0);
                d = (nb + dn) | (dfx << 16);                 // mode 0: two taps
            } else if (oku) {                                 // up==dn: w=1/3
                d = (nb + dn) | (1u << 12);
            } else {                                          // dn=99
                unsigned int dfx = (unsigned int)__double2int_rn(dec * 65535.0);
                d = (nb + dn) | (1u << 12) | (dfx << 16);     // mode 1: w=(1-dec)/3
            }
        }
        ((unsigned int*)(g_buf + OFF_DESC))[id] = d;
        return;
    }
    id -= NP * 10240;
    if (id < BB * TT * CIN) {   // x transpose
        int c = id % CIN, t = (id / CIN) % TT, b = id / (CIN * TT);
        g_buf[OFF_XT + (b * CIN + c) * TT + t] = x[id];
        return;
    }
    id -= BB * TT * CIN;
    if (id < BB * 12 * 256) {   // zero pfT pad rows t=100..111
        int c = id & 255, tp = (id >> 8) % 12, b = id / (12 * 256);
        ((unsigned short*)(g_buf + OFF_PFT))[((size_t)b * 112 + 100 + tp) * 256 + c] = 0;
    }
}
#define PREP_IDS (65536 + 147456 + 147456 + 51712 + NP * 10240 + BB * TT * CIN + BB * 12 * 256)

// ---------- conv1d k=3 pad=1 + relu ----------
template<int IPG, int OPG, int CINTOT>
__global__ void k_conv_t(int in_off, const float* __restrict__ w,
                         const float* __restrict__ bias, int out_off) {
    int id = blockIdx.x * 256 + threadIdx.x;
    if (id >= BB * H1 * TT) return;
    int t = id % TT, o = (id / TT) % H1, b = id / (TT * H1);
    const float* ip = g_buf + in_off + (b * CINTOT + (o / OPG) * IPG) * TT + t;
    const float* wp = w + o * IPG * 3;
    float acc = bias[o];
    bool t0 = (t > 0), t1 = (t < TT - 1);
    #pragma unroll 4
    for (int ci = 0; ci < IPG; ++ci) {
        float v0 = t0 ? ip[ci * TT - 1] : 0.f;
        float v1 = ip[ci * TT];
        float v2 = t1 ? ip[ci * TT + 1] : 0.f;
        acc = fmaf(v0, wp[ci * 3 + 0], acc);
        acc = fmaf(v1, wp[ci * 3 + 1], acc);
        acc = fmaf(v2, wp[ci * 3 + 2], acc);
    }
    g_buf[out_off + id] = fmaxf(acc, 0.f);
}

// ---------- pf conv (full 256->256) writing pfT bf16 directly ----------
__global__ void k_conv_pf(const float* __restrict__ w, const float* __restrict__ bias) {
    int id = blockIdx.x * 256 + threadIdx.x;
    if (id >= BB * H1 * TT) return;
    int t = id % TT, o = (id / TT) % H1, b = id / (TT * H1);
    const float* ip = g_buf + OFF_H2 + (b * H1) * TT + t;
    const float* wp = w + o * H1 * 3;
    float acc = bias[o];
    bool t0 = (t > 0), t1 = (t < TT - 1);
    #pragma unroll 4
    for (int ci = 0; ci < H1; ++ci) {
        float v0 = t0 ? ip[ci * TT - 1] : 0.f;
        float v1 = ip[ci * TT];
        float v2 = t1 ? ip[ci * TT + 1] : 0.f;
        acc = fmaf(v0, wp[ci * 3 + 0], acc);
        acc = fmaf(v1, wp[ci * 3 + 1], acc);
        acc = fmaf(v2, wp[ci * 3 + 2], acc);
    }
    ((unsigned short*)(g_buf + OFF_PFT))[((size_t)b * 112 + t) * 256 + o] =
        f2bf(fmaxf(acc, 0.f));
}

// ---------- both 1x1 sigmoid heads ----------
__global__ void k_heads(const float* __restrict__ ws2, const float* __restrict__ bs2,
                        const float* __restrict__ we2, const float* __restrict__ be2,
                        float* __restrict__ out) {
    int which = blockIdx.x;
    const float* w  = which ? we2 : ws2;
    const float* bi = which ? be2 : bs2;
    int in_off = which ? OFF_EB : OFF_SB;
    int id = threadIdx.x;
    if (id >= BB * TT) return;
    int t = id % TT, b = id / TT;
    const float* ip = g_buf + in_off + b * H1 * TT + t;
    float acc = bi[0];
    for (int c = 0; c < H1; ++c) acc = fmaf(ip[c * TT], w[c], acc);
    out[40000 + which * 200 + id] = 1.f / (1.f + expf(-acc));
}

// ---------- w3b[n][o][c] bf16 from w3d[o][c][n] ----------
__global__ __launch_bounds__(256) void k_w3prep(const float* __restrict__ w3d) {
    __shared__ float tile[8192];
    int o = blockIdx.x, tid = threadIdx.x;
    const float* src = w3d + o * 8192;
    for (int idx = tid; idx < 8192; idx += 256) tile[idx] = src[idx];
    __syncthreads();
    int n = tid & 31, ch = tid >> 5;
    unsigned short* w3b = (unsigned short*)(g_buf + OFF_W3B);
    unsigned int w[16];
    #pragma unroll
    for (int c2 = 0; c2 < 16; ++c2) {
        int c = ch * 32 + c2 * 2;
        w[c2] = (unsigned int)f2bf(tile[c * 32 + n]) |
                ((unsigned int)f2bf(tile[(c + 1) * 32 + n]) << 16);
    }
    uint4* dst = (uint4*)(w3b + ((size_t)n * 512 + o) * 256 + ch * 32);
    dst[0] = make_uint4(w[0], w[1], w[2], w[3]);
    dst[1] = make_uint4(w[4], w[5], w[6], w[7]);
    dst[2] = make_uint4(w[8], w[9], w[10], w[11]);
    dst[3] = make_uint4(w[12], w[13], w[14], w[15]);
}

// ---------- ATb2 pairs (MFMA) ----------
__global__ __launch_bounds__(256) void k_Am() {
    int mt = blockIdx.x, nt = blockIdx.y, bn = blockIdx.z;
    int b = bn >> 5, n = bn & 31;
    int wv = threadIdx.x >> 6, lane = threadIdx.x & 63;
    int r = lane & 15, g = lane >> 4;
    const unsigned short* ap = (const unsigned short*)(g_buf + OFF_PFT)
                               + ((size_t)b * 112 + mt * 16 + r) * 256 + g * 8;
    const unsigned short* bp = (const unsigned short*)(g_buf + OFF_W3B)
                               + ((size_t)n * 512 + nt * 128 + wv * 32 + r) * 256 + g * 8;
    f32x4 acc0 = {0.f, 0.f, 0.f, 0.f}, acc1 = {0.f, 0.f, 0.f, 0.f};
    #pragma unroll
    for (int ks = 0; ks < 8; ++ks) {
        bf16x8 a  = *(const bf16x8*)(ap + ks * 32);
        bf16x8 b0 = *(const bf16x8*)(bp + ks * 32);
        bf16x8 b1 = *(const bf16x8*)(bp + 16 * 256 + ks * 32);
        acc0 = __builtin_amdgcn_mfma_f32_16x16x32_bf16(a, b0, acc0, 0, 0, 0);
        acc1 = __builtin_amdgcn_mfma_f32_16x16x32_bf16(a, b1, acc1, 0, 0, 0);
    }
    unsigned short* ATb = (unsigned short*)(g_buf + OFF_ATB);
    int o0 = nt * 128 + wv * 32 + r, o1 = o0 + 16;
    #pragma unroll
    for (int reg = 0; reg < 4; ++reg) {
        int t = mt * 16 + g * 4 + reg;
        if (t < TT) {
            size_t m = (size_t)(n * 100 + t);
            unsigned short v0 = f2bf(acc0[reg] * (1.f / 3.f));
            unsigned short v1 = f2bf(acc1[reg] * (1.f / 3.f));
            size_t base0 = ((size_t)(b * 64 + (o0 >> 3)) * 3200 + m) * 16 + (o0 & 7) * 2;
            size_t base1 = ((size_t)(b * 64 + (o1 >> 3)) * 3200 + m) * 16 + (o1 & 7) * 2;
            ATb[base0] = v0;
            ATb[base1] = v1;
            if (t > 0) {
                ATb[base0 - 16 + 1] = v0;
                ATb[base1 - 16 + 1] = v1;
            }
            if (t == TT - 1) {
                ATb[base0 + 1] = 0;
                ATb[base1 + 1] = 0;
            }
        }
    }
}

// ---------- fill invalid (i>j) rows of cm2T with relu(b3d) ----------
__global__ void k_bmfill(const float* __restrict__ b3d) {
    int id = blockIdx.x * 256 + threadIdx.x;   // b * IJ * 64 chunks
    if (id >= BB * IJ * 64) return;
    int c8 = id & 63;
    int q = (id >> 6) % IJ;
    int b = id / (64 * IJ);
    int i = q / 100, j = q - i * 100;
    if (i <= j) return;
    unsigned int w[4];
    #pragma unroll
    for (int c2 = 0; c2 < 4; ++c2) {
        float v0 = fmaxf(b3d[c8 * 8 + c2 * 2], 0.f);
        float v1 = fmaxf(b3d[c8 * 8 + c2 * 2 + 1], 0.f);
        w[c2] = (unsigned int)f2bf(v0) | ((unsigned int)f2bf(v1) << 16);
    }
    *(uint4*)((unsigned short*)(g_buf + OFF_CM2T) + ((size_t)b * IJ + q) * 512 + c8 * 8) =
        make_uint4(w[0], w[1], w[2], w[3]);
}

// ---------- BM gather: valid (i<=j) q's only ----------
__global__ __launch_bounds__(256) void k_bm2(const float* __restrict__ b3d) {
    __shared__ uint4 Ash[1600];                 // 25.6 KB; slot = u ^ ((u>>3)&7)
    int qt = blockIdx.x, og = blockIdx.y, b = blockIdx.z;
    int tid = threadIdx.x;
    const unsigned int* desc = (const unsigned int*)(g_buf + OFF_DESC);
    const uint4* src = (const uint4*)((const unsigned short*)(g_buf + OFF_ATB)
                                      + (size_t)(b * 64 + og) * 3200 * 16);
    int q[2]; bool val[2];
    #pragma unroll
    for (int u = 0; u < 2; ++u) {
        int v = qt * 512 + u * 256 + tid;
        val[u] = (v < NVALID);
        int vv = val[u] ? v : 0;
        int i = (int)(100.5 - sqrt(10100.25 - 2.0 * (double)vv));
        if (i < 0) i = 0; if (i > 99) i = 99;
        while (100 * (i + 1) - ((i + 1) * i) / 2 <= vv && i < 99) ++i;
        while (100 * i - (i * (i - 1)) / 2 > vv && i > 0) --i;
        int j = i + (vv - (100 * i - (i * (i - 1)) / 2));
        q[u] = i * 100 + j;
    }
    float acc[2][8];
    #pragma unroll
    for (int u = 0; u < 2; ++u)
        #pragma unroll
        for (int c = 0; c < 8; ++c) acc[u][c] = 0.f;

    for (int st = 0; st < 4; ++st) {
        __syncthreads();
        for (int idx = tid; idx < 1600; idx += 256)
            Ash[idx ^ ((idx >> 3) & 7)] = src[st * 1600 + idx];
        __syncthreads();
        for (int kk = 0; kk < 24; ++kk) {
            const unsigned int* dk = desc + (size_t)(st * 24 + kk) * 10240;
            #pragma unroll
            for (int u = 0; u < 2; ++u) {
                unsigned int d = dk[q[u]];
                int t = (int)(d & 0xFFFu) - st * 800;
                unsigned int mode = (d >> 12) & 3u;
                float dec = (float)(d >> 16) * (1.f / 65535.f);
                float w0 = (mode == 2u) ? 0.f : 1.f - dec;
                float w1 = (mode == 0u) ? dec : 0.f;
                unsigned int wpair;
                asm("v_cvt_pk_bf16_f32 %0, %1, %2" : "=v"(wpair) : "v"(w0), "v"(w1));
                int u0 = t * 2;
                int s0 = u0 ^ ((u0 >> 3) & 7);
                uint4 A0 = Ash[s0];
                uint4 A1 = Ash[s0 ^ 1];
                dot2(acc[u][0], A0.x, wpair); dot2(acc[u][1], A0.y, wpair);
                dot2(acc[u][2], A0.z, wpair); dot2(acc[u][3], A0.w, wpair);
                dot2(acc[u][4], A1.x, wpair); dot2(acc[u][5], A1.y, wpair);
                dot2(acc[u][6], A1.z, wpair); dot2(acc[u][7], A1.w, wpair);
            }
        }
    }
    unsigned short* cm2T = (unsigned short*)(g_buf + OFF_CM2T);
    #pragma unroll
    for (int u = 0; u < 2; ++u) {
        if (val[u]) {
            unsigned int w[4];
            #pragma unroll
            for (int c2 = 0; c2 < 4; ++c2) {
                float v0 = fmaxf(acc[u][c2 * 2]     + b3d[og * 8 + c2 * 2],     0.f);
                float v1 = fmaxf(acc[u][c2 * 2 + 1] + b3d[og * 8 + c2 * 2 + 1], 0.f);
                w[c2] = (unsigned int)f2bf(v0) | ((unsigned int)f2bf(v1) << 16);
            }
            *(uint4*)(cm2T + ((size_t)b * IJ + q[u]) * 512 + og * 8) =
                make_uint4(w[0], w[1], w[2], w[3]);
        }
    }
}

// ---------- q1: 1x1 conv 512->128, MFMA ----------
__global__ __launch_bounds__(256) void k_q1m(const float* __restrict__ bias) {
    const unsigned short* A  = (const unsigned short*)(g_buf + OFF_CM2T);
    const unsigned short* Bw = (const unsigned short*)(g_buf + OFF_WQ1B);
    unsigned short* P1 = (unsigned short*)(g_buf + OFF_P1);
    int m0 = blockIdx.x * 16;
    int wv = threadIdx.x >> 6, lane = threadIdx.x & 63;
    int r = lane & 15, g = lane >> 4;
    int q0 = wv * 32;
    const unsigned short* arow  = A  + (size_t)(m0 + r) * 512 + g * 8;
    const unsigned short* b0row = Bw + (size_t)(q0 + r) * 512 + g * 8;
    const unsigned short* b1row = Bw + (size_t)(q0 + 16 + r) * 512 + g * 8;
    f32x4 acc0 = {0.f, 0.f, 0.f, 0.f}, acc1 = {0.f, 0.f, 0.f, 0.f};
    #pragma unroll 4
    for (int ks = 0; ks < 16; ++ks) {
        bf16x8 a  = *(const bf16x8*)(arow  + ks * 32);
        bf16x8 b0 = *(const bf16x8*)(b0row + ks * 32);
        bf16x8 b1 = *(const bf16x8*)(b1row + ks * 32);
        acc0 = __builtin_amdgcn_mfma_f32_16x16x32_bf16(a, b0, acc0, 0, 0, 0);
        acc1 = __builtin_amdgcn_mfma_f32_16x16x32_bf16(a, b1, acc1, 0, 0, 0);
    }
    int bb = m0 / IJ;
    unsigned short* Pout = P1 + (size_t)bb * PSTRIDE;
    float bi0 = bias[q0 + r], bi1 = bias[q0 + 16 + r];
    #pragma unroll
    for (int reg = 0; reg < 4; ++reg) {
        int p = m0 + g * 4 + reg;
        int ij = p - bb * IJ;
        int i = ij / 100, j = ij - i * 100;
        size_t base = (size_t)((i + 1) * PADW + j + 1) * H2C;
        Pout[base + q0 + r]      = f2bf(fmaxf(acc0[reg] + bi0, 0.f));
        Pout[base + q0 + 16 + r] = f2bf(fmaxf(acc1[reg] + bi1, 0.f));
    }
}

// ---------- 3x3 conv 128->128, MFMA implicit GEMM ----------
__global__ __launch_bounds__(256) void k_c3m(int in_off, int w_off,
                                             const float* __restrict__ bias,
                                             int out_off, int outpad) {
    const unsigned short* Pin = (const unsigned short*)(g_buf + in_off);
    const unsigned short* wB  = (const unsigned short*)(g_buf + w_off);
    unsigned short* Pout = (unsigned short*)(g_buf + out_off);
    int jt = blockIdx.x, i = blockIdx.y, b = blockIdx.z;
    int j0 = (jt == 6) ? 84 : jt * 16;
    int wv = threadIdx.x >> 6, lane = threadIdx.x & 63;
    int r = lane & 15, g = lane >> 4;
    int q0 = wv * 32;
    const unsigned short* Ab = Pin + (size_t)b * PSTRIDE;
    f32x4 acc0 = {0.f, 0.f, 0.f, 0.f}, acc1 = {0.f, 0.f, 0.f, 0.f};
    #pragma unroll 1
    for (int ky = 0; ky < 3; ++ky) {
        #pragma unroll
        for (int kx = 0; kx < 3; ++kx) {
            int tap = ky * 3 + kx;
            const unsigned short* arow = Ab + (size_t)((i + ky) * PADW + j0 + r + kx) * H2C + g * 8;
            const unsigned short* b0r = wB + (size_t)(q0 + r) * 1152 + tap * 128 + g * 8;
            const unsigned short* b1r = wB + (size_t)(q0 + 16 + r) * 1152 + tap * 128 + g * 8;
            #pragma unroll
            for (int cc = 0; cc < 4; ++cc) {
                bf16x8 a  = *(const bf16x8*)(arow + cc * 32);
                bf16x8 b0 = *(const bf16x8*)(b0r + cc * 32);
                bf16x8 b1 = *(const bf16x8*)(b1r + cc * 32);
                acc0 = __builtin_amdgcn_mfma_f32_16x16x32_bf16(a, b0, acc0, 0, 0, 0);
                acc1 = __builtin_amdgcn_mfma_f32_16x16x32_bf16(a, b1, acc1, 0, 0, 0);
            }
        }
    }
    float bi0 = bias[q0 + r], bi1 = bias[q0 + 16 + r];
    unsigned short* Ob = Pout + (size_t)b * (outpad ? (size_t)PSTRIDE : (size_t)IJ * H2C);
    #pragma unroll
    for (int reg = 0; reg < 4; ++reg) {
        int j = j0 + g * 4 + reg;
        size_t base = outpad ? (size_t)((i + 1) * PADW + j + 1) * H2C
                             : (size_t)(i * 100 + j) * H2C;
        Ob[base + q0 + r]      = f2bf(fmaxf(acc0[reg] + bi0, 0.f));
        Ob[base + q0 + 16 + r] = f2bf(fmaxf(acc1[reg] + bi1, 0.f));
    }
}

// ---------- q4: 1x1 conv 128->2 + sigmoid ----------
__global__ void k_q4(const float* __restrict__ w, const float* __restrict__ bias,
                     float* __restrict__ out) {
    int id = blockIdx.x * 256 + threadIdx.x;
    if (id >= BB * IJ) return;
    int b = id / IJ, ij = id % IJ;
    const unsigned short* row = (const unsigned short*)(g_buf + OFF_P3) + (size_t)id * H2C;
    float a0 = bias[0], a1 = bias[1];
    for (int c = 0; c < H2C; c += 8) {
        bf16x8 v = *(const bf16x8*)(row + c);
        #pragma unroll
        for (int t = 0; t < 8; ++t) {
            float f = bf2f((unsigned short)v[t]);
            a0 = fmaf(f, w[c + t], a0);
            a1 = fmaf(f, w[128 + c + t], a1);
        }
    }
    out[(size_t)(b * 2) * IJ + ij]     = 1.f / (1.f + expf(-a0));
    out[(size_t)(b * 2 + 1) * IJ + ij] = 1.f / (1.f + expf(-a1));
}

extern "C" void kernel_launch(void* const* d_in, const int* in_sizes, int n_in,
                              void* d_out, int out_size, void* d_ws, size_t ws_size,
                              hipStream_t stream) {
    const float* x   = (const float*)d_in[0];
    const float* wb1 = (const float*)d_in[1];  const float* bb1 = (const float*)d_in[2];
    const float* wb2 = (const float*)d_in[3];  const float* bb2 = (const float*)d_in[4];
    const float* ws1 = (const float*)d_in[5];  const float* bs1 = (const float*)d_in[6];
    const float* ws2 = (const float*)d_in[7];  const float* bs2 = (const float*)d_in[8];
    const float* we1 = (const float*)d_in[9];  const float* be1 = (const float*)d_in[10];
    const float* we2 = (const float*)d_in[11]; const float* be2 = (const float*)d_in[12];
    const float* wp  = (const float*)d_in[13]; const float* bp  = (const float*)d_in[14];
    const float* w3d = (const float*)d_in[15]; const float* b3d = (const float*)d_in[16];
    const float* wq1 = (const float*)d_in[17]; const float* bq1 = (const float*)d_in[18];
    const float* wq2 = (const float*)d_in[19]; const float* bq2 = (const float*)d_in[20];
    const float* wq3 = (const float*)d_in[21]; const float* bq3 = (const float*)d_in[22];
    const float* wq4 = (const float*)d_in[23]; const float* bq4 = (const float*)d_in[24];
    float* out = (float*)d_out;

    k_prep<<<(PREP_IDS + 255) / 256, 256, 0, stream>>>(wq1, wq2, wq3, x);
    k_w3prep<<<512, 256, 0, stream>>>(w3d);
    k_bmfill<<<(BB * IJ * 64 + 255) / 256, 256, 0, stream>>>(b3d);
    k_conv_t<100, 64, 400><<<200, 256, 0, stream>>>(OFF_XT, wb1, bb1, OFF_H1);
    k_conv_t<64, 64, 256><<<200, 256, 0, stream>>>(OFF_H1, wb2, bb2, OFF_H2);
    k_conv_t<64, 64, 256><<<200, 256, 0, stream>>>(OFF_H2, ws1, bs1, OFF_SB);
    k_conv_t<64, 64, 256><<<200, 256, 0, stream>>>(OFF_H2, we1, be1, OFF_EB);
    k_heads<<<2, 256, 0, stream>>>(ws2, bs2, we2, be2, out);
    k_conv_pf<<<200, 256, 0, stream>>>(wp, bp);
    k_Am<<<dim3(7, 4, 64), 256, 0, stream>>>();
    k_bm2<<<dim3(10, 64, 2), 256, 0, stream>>>(b3d);
    k_q1m<<<1250, 256, 0, stream>>>(bq1);
    k_c3m<<<dim3(7, 100, 2), 256, 0, stream>>>(OFF_P1, OFF_WQ2B, bq2, OFF_P2, 1);
    k_c3m<<<dim3(7, 100, 2), 256, 0, stream>>>(OFF_P2, OFF_WQ3B, bq3, OFF_P3, 0);
    k_q4<<<(BB * IJ + 255) / 256, 256, 0, stream>>>(wq4, bq4, out);
}

// Round 8
// 287.105 us; speedup vs baseline: 4.2526x; 1.2934x over previous
//
#include <hip/hip_runtime.h>
#include <hip/hip_bf16.h>
#include <math.h>

#define TT  100
#define CIN 400
#define H1  256
#define NS  32
#define NP  96
#define H3  512
#define H2C 128
#define BB  2
#define IJ  10000
#define NVALID 5050
#define PADW 102
#define PPIX 10432
#define PSTRIDE (PPIX * H2C)

typedef __attribute__((ext_vector_type(8))) short bf16x8;
typedef __attribute__((ext_vector_type(4))) float f32x4;

// ---- static scratch (float units) ----
#define OFF_XT   0
#define OFF_H1   80000
#define OFF_H2   131200
#define OFF_SB   182400
#define OFF_EB   233600
#define OFF_PF   284800
#define OFF_ATB  336000      // bf16 pairs ATb2[b][64][3200][8][2]
#define OFF_CM2T 3612800     // bf16 [b][ij][512]
#define OFF_P1   8732800
#define OFF_P2   10068096
#define OFF_P3   11403392
#define OFF_WQ1B 12683392
#define OFF_WQ2B 12716160
#define OFF_WQ3B 12789888
#define OFF_DESC 12863616    // u32 [96][10240]
#define OFF_PFT  13846656    // bf16 [b][112][256]
#define OFF_W3B  13875328    // bf16 [n][o][c]
#define G_TOTAL  15972480

__device__ __align__(16) float g_buf[G_TOTAL];

__device__ inline unsigned short f2bf(float f) {
    __hip_bfloat16 h = __float2bfloat16(f);
    return *(unsigned short*)&h;
}
__device__ inline float bf2f(unsigned short u) {
    union { unsigned int i; float f; } v; v.i = ((unsigned int)u) << 16; return v.f;
}
__device__ inline void dot2(float& acc, unsigned int a, unsigned int w) {
    asm("v_dot2_f32_bf16 %0, %1, %2, %0" : "+v"(acc) : "v"(a), "v"(w));
}

// ---------- merged prep ----------
__global__ void k_prep(const float* __restrict__ wq1, const float* __restrict__ wq2,
                       const float* __restrict__ wq3, const float* __restrict__ x) {
    int id = blockIdx.x * 256 + threadIdx.x;
    if (id < 65536) {
        ((unsigned short*)(g_buf + OFF_WQ1B))[id] = f2bf(wq1[id]);
        return;
    }
    id -= 65536;
    if (id < 147456) {
        int q = id / 1152, k = id % 1152, tap = k >> 7, c = k & 127;
        ((unsigned short*)(g_buf + OFF_WQ2B))[id] = f2bf(wq2[(q * 128 + c) * 9 + tap]);
        return;
    }
    id -= 147456;
    if (id < 147456) {
        int q = id / 1152, k = id % 1152, tap = k >> 7, c = k & 127;
        ((unsigned short*)(g_buf + OFF_WQ3B))[id] = f2bf(wq3[(q * 128 + c) * 9 + tap]);
        return;
    }
    id -= 147456;
    if (id < 51712) {   // halo zero
        int c = id & 31;
        int h = (id >> 5) % 404;
        int bb = ((id >> 5) / 404) & 1;
        int buf = id / 25856;
        int pix;
        if (h < 102) pix = h;
        else if (h < 204) pix = 101 * PADW + (h - 102);
        else { int q = h - 204; pix = (1 + (q >> 1)) * PADW + ((q & 1) ? 101 : 0); }
        unsigned short* P = (unsigned short*)(g_buf + (buf ? OFF_P2 : OFF_P1))
                            + (size_t)bb * PSTRIDE + (size_t)pix * H2C;
        ((uint2*)P)[c] = make_uint2(0u, 0u);
        return;
    }
    id -= 51712;
    if (id < NP * 10240) {   // desc
        int k = id / 10240, q = id - k * 10240;
        int i = q / 100, j = q - i * 100;
        unsigned int nb = (unsigned int)((k / 3) * 100);
        unsigned int d;
        if (q >= IJ || i > j) {
            d = nb | (2u << 12);
        } else {
            double len = (double)(j - i + 2);
            double xmn = (double)i - 0.5 * len;
            double xmx = (double)(j + 1) + 0.5 * len;
            double plen = (xmx - xmn) / 95.0;
            double s = __dadd_rn(xmn, __dmul_rn(plen, (double)k));
            double tr = trunc(s);
            double dec = s - tr;
            int dn = (int)tr;
            int up = (int)ceil(s);
            bool okd = (unsigned)dn < (unsigned)TT;
            bool oku = (unsigned)up < (unsigned)TT;
            if (!okd) d = nb | (2u << 12);
            else if (oku && up == dn + 1) {
                unsigned int dfx = (unsigned int)__double2int_rn(dec * 65535.0);
                d = (nb + dn) | (dfx << 16);
            } else if (oku) {
                d = (nb + dn) | (1u << 12);
            } else {
                unsigned int dfx = (unsigned int)__double2int_rn(dec * 65535.0);
                d = (nb + dn) | (1u << 12) | (dfx << 16);
            }
        }
        ((unsigned int*)(g_buf + OFF_DESC))[id] = d;
        return;
    }
    id -= NP * 10240;
    if (id < BB * TT * CIN) {   // x transpose
        int c = id % CIN, t = (id / CIN) % TT, b = id / (CIN * TT);
        g_buf[OFF_XT + (b * CIN + c) * TT + t] = x[id];
        return;
    }
    id -= BB * TT * CIN;
    if (id < BB * 12 * 256) {   // zero pfT pad rows
        int c = id & 255, tp = (id >> 8) % 12, b = id / (12 * 256);
        ((unsigned short*)(g_buf + OFF_PFT))[((size_t)b * 112 + 100 + tp) * 256 + c] = 0;
    }
}
#define PREP_IDS (65536 + 147456 + 147456 + 51712 + NP * 10240 + BB * TT * CIN + BB * 12 * 256)

// ---------- conv1d k=3 pad=1 + relu ----------
template<int IPG, int OPG, int CINTOT>
__global__ void k_conv_t(int in_off, const float* __restrict__ w,
                         const float* __restrict__ bias, int out_off) {
    int id = blockIdx.x * 256 + threadIdx.x;
    if (id >= BB * H1 * TT) return;
    int t = id % TT, o = (id / TT) % H1, b = id / (TT * H1);
    const float* ip = g_buf + in_off + (b * CINTOT + (o / OPG) * IPG) * TT + t;
    const float* wp = w + o * IPG * 3;
    float acc = bias[o];
    bool t0 = (t > 0), t1 = (t < TT - 1);
    #pragma unroll 4
    for (int ci = 0; ci < IPG; ++ci) {
        float v0 = t0 ? ip[ci * TT - 1] : 0.f;
        float v1 = ip[ci * TT];
        float v2 = t1 ? ip[ci * TT + 1] : 0.f;
        acc = fmaf(v0, wp[ci * 3 + 0], acc);
        acc = fmaf(v1, wp[ci * 3 + 1], acc);
        acc = fmaf(v2, wp[ci * 3 + 2], acc);
    }
    g_buf[out_off + id] = fmaxf(acc, 0.f);
}

// ---------- pf conv writing pfT bf16 directly ----------
__global__ void k_conv_pf(const float* __restrict__ w, const float* __restrict__ bias) {
    int id = blockIdx.x * 256 + threadIdx.x;
    if (id >= BB * H1 * TT) return;
    int t = id % TT, o = (id / TT) % H1, b = id / (TT * H1);
    const float* ip = g_buf + OFF_H2 + (b * H1) * TT + t;
    const float* wp = w + o * H1 * 3;
    float acc = bias[o];
    bool t0 = (t > 0), t1 = (t < TT - 1);
    #pragma unroll 4
    for (int ci = 0; ci < H1; ++ci) {
        float v0 = t0 ? ip[ci * TT - 1] : 0.f;
        float v1 = ip[ci * TT];
        float v2 = t1 ? ip[ci * TT + 1] : 0.f;
        acc = fmaf(v0, wp[ci * 3 + 0], acc);
        acc = fmaf(v1, wp[ci * 3 + 1], acc);
        acc = fmaf(v2, wp[ci * 3 + 2], acc);
    }
    ((unsigned short*)(g_buf + OFF_PFT))[((size_t)b * 112 + t) * 256 + o] =
        f2bf(fmaxf(acc, 0.f));
}

// ---------- both 1x1 sigmoid heads ----------
__global__ void k_heads(const float* __restrict__ ws2, const float* __restrict__ bs2,
                        const float* __restrict__ we2, const float* __restrict__ be2,
                        float* __restrict__ out) {
    int which = blockIdx.x;
    const float* w  = which ? we2 : ws2;
    const float* bi = which ? be2 : bs2;
    int in_off = which ? OFF_EB : OFF_SB;
    int id = threadIdx.x;
    if (id >= BB * TT) return;
    int t = id % TT, b = id / TT;
    const float* ip = g_buf + in_off + b * H1 * TT + t;
    float acc = bi[0];
    for (int c = 0; c < H1; ++c) acc = fmaf(ip[c * TT], w[c], acc);
    out[40000 + which * 200 + id] = 1.f / (1.f + expf(-acc));
}

// ---------- w3b[n][o][c] bf16 from w3d[o][c][n] ----------
__global__ __launch_bounds__(256) void k_w3prep(const float* __restrict__ w3d) {
    __shared__ float tile[8192];
    int o = blockIdx.x, tid = threadIdx.x;
    const float* src = w3d + o * 8192;
    for (int idx = tid; idx < 8192; idx += 256) tile[idx] = src[idx];
    __syncthreads();
    int n = tid & 31, ch = tid >> 5;
    unsigned short* w3b = (unsigned short*)(g_buf + OFF_W3B);
    unsigned int w[16];
    #pragma unroll
    for (int c2 = 0; c2 < 16; ++c2) {
        int c = ch * 32 + c2 * 2;
        w[c2] = (unsigned int)f2bf(tile[c * 32 + n]) |
                ((unsigned int)f2bf(tile[(c + 1) * 32 + n]) << 16);
    }
    uint4* dst = (uint4*)(w3b + ((size_t)n * 512 + o) * 256 + ch * 32);
    dst[0] = make_uint4(w[0], w[1], w[2], w[3]);
    dst[1] = make_uint4(w[4], w[5], w[6], w[7]);
    dst[2] = make_uint4(w[8], w[9], w[10], w[11]);
    dst[3] = make_uint4(w[12], w[13], w[14], w[15]);
}

// ---------- ATb2 pairs (MFMA) ----------
__global__ __launch_bounds__(256) void k_Am() {
    int mt = blockIdx.x, nt = blockIdx.y, bn = blockIdx.z;
    int b = bn >> 5, n = bn & 31;
    int wv = threadIdx.x >> 6, lane = threadIdx.x & 63;
    int r = lane & 15, g = lane >> 4;
    const unsigned short* ap = (const unsigned short*)(g_buf + OFF_PFT)
                               + ((size_t)b * 112 + mt * 16 + r) * 256 + g * 8;
    const unsigned short* bp = (const unsigned short*)(g_buf + OFF_W3B)
                               + ((size_t)n * 512 + nt * 128 + wv * 32 + r) * 256 + g * 8;
    f32x4 acc0 = {0.f, 0.f, 0.f, 0.f}, acc1 = {0.f, 0.f, 0.f, 0.f};
    #pragma unroll
    for (int ks = 0; ks < 8; ++ks) {
        bf16x8 a  = *(const bf16x8*)(ap + ks * 32);
        bf16x8 b0 = *(const bf16x8*)(bp + ks * 32);
        bf16x8 b1 = *(const bf16x8*)(bp + 16 * 256 + ks * 32);
        acc0 = __builtin_amdgcn_mfma_f32_16x16x32_bf16(a, b0, acc0, 0, 0, 0);
        acc1 = __builtin_amdgcn_mfma_f32_16x16x32_bf16(a, b1, acc1, 0, 0, 0);
    }
    unsigned short* ATb = (unsigned short*)(g_buf + OFF_ATB);
    int o0 = nt * 128 + wv * 32 + r, o1 = o0 + 16;
    #pragma unroll
    for (int reg = 0; reg < 4; ++reg) {
        int t = mt * 16 + g * 4 + reg;
        if (t < TT) {
            size_t m = (size_t)(n * 100 + t);
            unsigned short v0 = f2bf(acc0[reg] * (1.f / 3.f));
            unsigned short v1 = f2bf(acc1[reg] * (1.f / 3.f));
            size_t base0 = ((size_t)(b * 64 + (o0 >> 3)) * 3200 + m) * 16 + (o0 & 7) * 2;
            size_t base1 = ((size_t)(b * 64 + (o1 >> 3)) * 3200 + m) * 16 + (o1 & 7) * 2;
            ATb[base0] = v0;
            ATb[base1] = v1;
            if (t > 0) {
                ATb[base0 - 16 + 1] = v0;
                ATb[base1 - 16 + 1] = v1;
            }
            if (t == TT - 1) {
                ATb[base0 + 1] = 0;
                ATb[base1 + 1] = 0;
            }
        }
    }
}

// ---------- fill invalid (i>j) rows of cm2T ----------
__global__ void k_bmfill(const float* __restrict__ b3d) {
    int id = blockIdx.x * 256 + threadIdx.x;
    if (id >= BB * IJ * 64) return;
    int c8 = id & 63;
    int q = (id >> 6) % IJ;
    int b = id / (64 * IJ);
    int i = q / 100, j = q - i * 100;
    if (i <= j) return;
    unsigned int w[4];
    #pragma unroll
    for (int c2 = 0; c2 < 4; ++c2) {
        float v0 = fmaxf(b3d[c8 * 8 + c2 * 2], 0.f);
        float v1 = fmaxf(b3d[c8 * 8 + c2 * 2 + 1], 0.f);
        w[c2] = (unsigned int)f2bf(v0) | ((unsigned int)f2bf(v1) << 16);
    }
    *(uint4*)((unsigned short*)(g_buf + OFF_CM2T) + ((size_t)b * IJ + q) * 512 + c8 * 8) =
        make_uint4(w[0], w[1], w[2], w[3]);
}

// ---------- BM gather: valid q's only ----------
__global__ __launch_bounds__(256) void k_bm2(const float* __restrict__ b3d) {
    __shared__ uint4 Ash[1600];
    int qt = blockIdx.x, og = blockIdx.y, b = blockIdx.z;
    int tid = threadIdx.x;
    const unsigned int* desc = (const unsigned int*)(g_buf + OFF_DESC);
    const uint4* src = (const uint4*)((const unsigned short*)(g_buf + OFF_ATB)
                                      + (size_t)(b * 64 + og) * 3200 * 16);
    int q[2]; bool val[2];
    #pragma unroll
    for (int u = 0; u < 2; ++u) {
        int v = qt * 512 + u * 256 + tid;
        val[u] = (v < NVALID);
        int vv = val[u] ? v : 0;
        int i = (int)(100.5 - sqrt(10100.25 - 2.0 * (double)vv));
        if (i < 0) i = 0; if (i > 99) i = 99;
        while (100 * (i + 1) - ((i + 1) * i) / 2 <= vv && i < 99) ++i;
        while (100 * i - (i * (i - 1)) / 2 > vv && i > 0) --i;
        int j = i + (vv - (100 * i - (i * (i - 1)) / 2));
        q[u] = i * 100 + j;
    }
    float acc[2][8];
    #pragma unroll
    for (int u = 0; u < 2; ++u)
        #pragma unroll
        for (int c = 0; c < 8; ++c) acc[u][c] = 0.f;

    for (int st = 0; st < 4; ++st) {
        __syncthreads();
        for (int idx = tid; idx < 1600; idx += 256)
            Ash[idx ^ ((idx >> 3) & 7)] = src[st * 1600 + idx];
        __syncthreads();
        for (int kk = 0; kk < 24; ++kk) {
            const unsigned int* dk = desc + (size_t)(st * 24 + kk) * 10240;
            #pragma unroll
            for (int u = 0; u < 2; ++u) {
                unsigned int d = dk[q[u]];
                int t = (int)(d & 0xFFFu) - st * 800;
                unsigned int mode = (d >> 12) & 3u;
                float dec = (float)(d >> 16) * (1.f / 65535.f);
                float w0 = (mode == 2u) ? 0.f : 1.f - dec;
                float w1 = (mode == 0u) ? dec : 0.f;
                unsigned int wpair;
                asm("v_cvt_pk_bf16_f32 %0, %1, %2" : "=v"(wpair) : "v"(w0), "v"(w1));
                int u0 = t * 2;
                int s0 = u0 ^ ((u0 >> 3) & 7);
                uint4 A0 = Ash[s0];
                uint4 A1 = Ash[s0 ^ 1];
                dot2(acc[u][0], A0.x, wpair); dot2(acc[u][1], A0.y, wpair);
                dot2(acc[u][2], A0.z, wpair); dot2(acc[u][3], A0.w, wpair);
                dot2(acc[u][4], A1.x, wpair); dot2(acc[u][5], A1.y, wpair);
                dot2(acc[u][6], A1.z, wpair); dot2(acc[u][7], A1.w, wpair);
            }
        }
    }
    unsigned short* cm2T = (unsigned short*)(g_buf + OFF_CM2T);
    #pragma unroll
    for (int u = 0; u < 2; ++u) {
        if (val[u]) {
            unsigned int w[4];
            #pragma unroll
            for (int c2 = 0; c2 < 4; ++c2) {
                float v0 = fmaxf(acc[u][c2 * 2]     + b3d[og * 8 + c2 * 2],     0.f);
                float v1 = fmaxf(acc[u][c2 * 2 + 1] + b3d[og * 8 + c2 * 2 + 1], 0.f);
                w[c2] = (unsigned int)f2bf(v0) | ((unsigned int)f2bf(v1) << 16);
            }
            *(uint4*)(cm2T + ((size_t)b * IJ + q[u]) * 512 + og * 8) =
                make_uint4(w[0], w[1], w[2], w[3]);
        }
    }
}

#define MFMA16(a, b, c) __builtin_amdgcn_mfma_f32_16x16x32_bf16(a, b, c, 0, 0, 0)

// ---------- q1: 1x1 conv 512->128, pipelined GEMM, M=32/block ----------
__global__ __launch_bounds__(256) void k_q1m(const float* __restrict__ bias) {
    __shared__ uint4 As[2048];                  // 32 px x 64 chunks, swizzled
    const unsigned short* Acm = (const unsigned short*)(g_buf + OFF_CM2T);
    const unsigned short* Bw  = (const unsigned short*)(g_buf + OFF_WQ1B);
    unsigned short* P1 = (unsigned short*)(g_buf + OFF_P1);
    int m0 = blockIdx.x * 32, b = blockIdx.y;
    int tid = threadIdx.x;
    for (int idx = tid; idx < 2048; idx += 256) {
        int px = idx >> 6, ch = idx & 63;
        int srow = m0 + px; if (srow > IJ - 1) srow = IJ - 1;
        int ch2 = ch ^ (px & 7) ^ (((px >> 3) & 1) << 3);
        As[px * 64 + ch2] = *(const uint4*)(Acm + ((size_t)b * IJ + srow) * 512 + ch * 8);
    }
    __syncthreads();
    int wv = tid >> 6, lane = tid & 63, r = lane & 15, g = lane >> 4;
    int q0 = wv * 32;
    f32x4 acc[2][2] = {{{0.f,0.f,0.f,0.f},{0.f,0.f,0.f,0.f}},{{0.f,0.f,0.f,0.f},{0.f,0.f,0.f,0.f}}};
    bf16x8 Bb[4][2], Aa[2][2];
#define Q1_LB(slot, it_) { const unsigned short* bp = Bw + (size_t)(q0 + r) * 512 + (it_) * 32 + g * 8; \
    Bb[slot][0] = *(const bf16x8*)bp; Bb[slot][1] = *(const bf16x8*)(bp + 16 * 512); }
#define Q1_LA(slot, it_) { int ch = (it_) * 4 + g; \
    int px0 = r, px1 = 16 + r; \
    Aa[slot][0] = *(const bf16x8*)&As[px0 * 64 + (ch ^ (px0 & 7) ^ (((px0 >> 3) & 1) << 3))]; \
    Aa[slot][1] = *(const bf16x8*)&As[px1 * 64 + (ch ^ (px1 & 7) ^ (((px1 >> 3) & 1) << 3))]; }
    Q1_LB(0, 0); Q1_LB(1, 1); Q1_LB(2, 2); Q1_LA(0, 0);
    #pragma unroll
    for (int it = 0; it < 16; ++it) {
        if (it + 3 < 16) Q1_LB((it + 3) & 3, it + 3);
        if (it + 1 < 16) Q1_LA((it + 1) & 1, it + 1);
        int s = it & 3, sa = it & 1;
        acc[0][0] = MFMA16(Aa[sa][0], Bb[s][0], acc[0][0]);
        acc[0][1] = MFMA16(Aa[sa][0], Bb[s][1], acc[0][1]);
        acc[1][0] = MFMA16(Aa[sa][1], Bb[s][0], acc[1][0]);
        acc[1][1] = MFMA16(Aa[sa][1], Bb[s][1], acc[1][1]);
    }
    float bi0 = bias[q0 + r], bi1 = bias[q0 + 16 + r];
    unsigned short* Pout = P1 + (size_t)b * PSTRIDE;
    #pragma unroll
    for (int mt = 0; mt < 2; ++mt)
        #pragma unroll
        for (int reg = 0; reg < 4; ++reg) {
            int p = m0 + mt * 16 + g * 4 + reg;
            if (p < IJ) {
                int i = p / 100, j = p - i * 100;
                size_t base = (size_t)((i + 1) * PADW + j + 1) * H2C;
                Pout[base + q0 + r]      = f2bf(fmaxf(acc[mt][0][reg] + bi0, 0.f));
                Pout[base + q0 + 16 + r] = f2bf(fmaxf(acc[mt][1][reg] + bi1, 0.f));
            }
        }
}

// ---------- 3x3 conv 128->128, pipelined implicit GEMM, M=32/block ----------
__global__ __launch_bounds__(256) void k_c3m(int in_off, int w_off,
                                             const float* __restrict__ bias,
                                             int out_off, int outpad) {
    __shared__ uint4 As[1632];                  // 3 rows x 34 px x 16 chunks, swizzled
    const unsigned short* Pin = (const unsigned short*)(g_buf + in_off);
    const unsigned short* wB  = (const unsigned short*)(g_buf + w_off);
    unsigned short* Pout = (unsigned short*)(g_buf + out_off);
    int jt = blockIdx.x, i = blockIdx.y, b = blockIdx.z;
    int j0 = (jt == 3) ? 68 : jt * 32;
    int tid = threadIdx.x;
    const unsigned short* Ab = Pin + (size_t)b * PSTRIDE;
    for (int idx = tid; idx < 1632; idx += 256) {
        int ky = idx / 544, rem = idx - ky * 544;
        int px = rem >> 4, ch = rem & 15;
        int ch2 = ch ^ (px & 7) ^ (((px >> 3) & 1) << 3);
        As[(ky * 34 + px) * 16 + ch2] =
            *(const uint4*)(Ab + (size_t)((i + ky) * PADW + j0 + px) * H2C + ch * 8);
    }
    __syncthreads();
    int wv = tid >> 6, lane = tid & 63, r = lane & 15, g = lane >> 4;
    int q0 = wv * 32;
    f32x4 acc[2][2] = {{{0.f,0.f,0.f,0.f},{0.f,0.f,0.f,0.f}},{{0.f,0.f,0.f,0.f},{0.f,0.f,0.f,0.f}}};
    bf16x8 Bb[4][2], Aa[2][2];
#define C3_LB(slot, it_) { int tap = (it_) >> 2, cc = (it_) & 3; \
    const unsigned short* bp = wB + (size_t)(q0 + r) * 1152 + tap * 128 + cc * 32 + g * 8; \
    Bb[slot][0] = *(const bf16x8*)bp; Bb[slot][1] = *(const bf16x8*)(bp + 16 * 1152); }
#define C3_LA(slot, it_) { int tap = (it_) >> 2, cc = (it_) & 3; \
    int ky = tap / 3, kx = tap - ky * 3; int ch = cc * 4 + g; \
    int px0 = r + kx, px1 = 16 + r + kx; \
    Aa[slot][0] = *(const bf16x8*)&As[(ky * 34 + px0) * 16 + (ch ^ (px0 & 7) ^ (((px0 >> 3) & 1) << 3))]; \
    Aa[slot][1] = *(const bf16x8*)&As[(ky * 34 + px1) * 16 + (ch ^ (px1 & 7) ^ (((px1 >> 3) & 1) << 3))]; }
    C3_LB(0, 0); C3_LB(1, 1); C3_LB(2, 2); C3_LA(0, 0);
    #pragma unroll
    for (int it = 0; it < 36; ++it) {
        if (it + 3 < 36) C3_LB((it + 3) & 3, it + 3);
        if (it + 1 < 36) C3_LA((it + 1) & 1, it + 1);
        int s = it & 3, sa = it & 1;
        acc[0][0] = MFMA16(Aa[sa][0], Bb[s][0], acc[0][0]);
        acc[0][1] = MFMA16(Aa[sa][0], Bb[s][1], acc[0][1]);
        acc[1][0] = MFMA16(Aa[sa][1], Bb[s][0], acc[1][0]);
        acc[1][1] = MFMA16(Aa[sa][1], Bb[s][1], acc[1][1]);
    }
    float bi0 = bias[q0 + r], bi1 = bias[q0 + 16 + r];
    unsigned short* Ob = Pout + (size_t)b * (outpad ? (size_t)PSTRIDE : (size_t)IJ * H2C);
    #pragma unroll
    for (int mt = 0; mt < 2; ++mt)
        #pragma unroll
        for (int reg = 0; reg < 4; ++reg) {
            int j = j0 + mt * 16 + g * 4 + reg;
            size_t base = outpad ? (size_t)((i + 1) * PADW + j + 1) * H2C
                                 : (size_t)(i * 100 + j) * H2C;
            Ob[base + q0 + r]      = f2bf(fmaxf(acc[mt][0][reg] + bi0, 0.f));
            Ob[base + q0 + 16 + r] = f2bf(fmaxf(acc[mt][1][reg] + bi1, 0.f));
        }
}

// ---------- q4: 1x1 conv 128->2 + sigmoid ----------
__global__ void k_q4(const float* __restrict__ w, const float* __restrict__ bias,
                     float* __restrict__ out) {
    int id = blockIdx.x * 256 + threadIdx.x;
    if (id >= BB * IJ) return;
    int b = id / IJ, ij = id % IJ;
    const unsigned short* row = (const unsigned short*)(g_buf + OFF_P3) + (size_t)id * H2C;
    float a0 = bias[0], a1 = bias[1];
    for (int c = 0; c < H2C; c += 8) {
        bf16x8 v = *(const bf16x8*)(row + c);
        #pragma unroll
        for (int t = 0; t < 8; ++t) {
            float f = bf2f((unsigned short)v[t]);
            a0 = fmaf(f, w[c + t], a0);
            a1 = fmaf(f, w[128 + c + t], a1);
        }
    }
    out[(size_t)(b * 2) * IJ + ij]     = 1.f / (1.f + expf(-a0));
    out[(size_t)(b * 2 + 1) * IJ + ij] = 1.f / (1.f + expf(-a1));
}

extern "C" void kernel_launch(void* const* d_in, const int* in_sizes, int n_in,
                              void* d_out, int out_size, void* d_ws, size_t ws_size,
                              hipStream_t stream) {
    const float* x   = (const float*)d_in[0];
    const float* wb1 = (const float*)d_in[1];  const float* bb1 = (const float*)d_in[2];
    const float* wb2 = (const float*)d_in[3];  const float* bb2 = (const float*)d_in[4];
    const float* ws1 = (const float*)d_in[5];  const float* bs1 = (const float*)d_in[6];
    const float* ws2 = (const float*)d_in[7];  const float* bs2 = (const float*)d_in[8];
    const float* we1 = (const float*)d_in[9];  const float* be1 = (const float*)d_in[10];
    const float* we2 = (const float*)d_in[11]; const float* be2 = (const float*)d_in[12];
    const float* wp  = (const float*)d_in[13]; const float* bp  = (const float*)d_in[14];
    const float* w3d = (const float*)d_in[15]; const float* b3d = (const float*)d_in[16];
    const float* wq1 = (const float*)d_in[17]; const float* bq1 = (const float*)d_in[18];
    const float* wq2 = (const float*)d_in[19]; const float* bq2 = (const float*)d_in[20];
    const float* wq3 = (const float*)d_in[21]; const float* bq3 = (const float*)d_in[22];
    const float* wq4 = (const float*)d_in[23]; const float* bq4 = (const float*)d_in[24];
    float* out = (float*)d_out;

    k_prep<<<(PREP_IDS + 255) / 256, 256, 0, stream>>>(wq1, wq2, wq3, x);
    k_w3prep<<<512, 256, 0, stream>>>(w3d);
    k_bmfill<<<(BB * IJ * 64 + 255) / 256, 256, 0, stream>>>(b3d);
    k_conv_t<100, 64, 400><<<200, 256, 0, stream>>>(OFF_XT, wb1, bb1, OFF_H1);
    k_conv_t<64, 64, 256><<<200, 256, 0, stream>>>(OFF_H1, wb2, bb2, OFF_H2);
    k_conv_t<64, 64, 256><<<200, 256, 0, stream>>>(OFF_H2, ws1, bs1, OFF_SB);
    k_conv_t<64, 64, 256><<<200, 256, 0, stream>>>(OFF_H2, we1, be1, OFF_EB);
    k_heads<<<2, 256, 0, stream>>>(ws2, bs2, we2, be2, out);
    k_conv_pf<<<200, 256, 0, stream>>>(wp, bp);
    k_Am<<<dim3(7, 4, 64), 256, 0, stream>>>();
    k_bm2<<<dim3(10, 64, 2), 256, 0, stream>>>(b3d);
    k_q1m<<<dim3(313, 2), 256, 0, stream>>>(bq1);
    k_c3m<<<dim3(4, 100, 2), 256, 0, stream>>>(OFF_P1, OFF_WQ2B, bq2, OFF_P2, 1);
    k_c3m<<<dim3(4, 100, 2), 256, 0, stream>>>(OFF_P2, OFF_WQ3B, bq3, OFF_P3, 0);
    k_q4<<<(BB * IJ + 255) / 256, 256, 0, stream>>>(wq4, bq4, out);
}